// Round 1
// baseline (895.003 us; speedup 1.0000x reference)
//
#include <hip/hip_runtime.h>
#include <hip/hip_bf16.h>
#include <cstdint>
#include <cstddef>

#define BN_EPS 1e-5f

// ---------------------------------------------------------------------------
// int64-vs-int32 edge dtype detection.
// If edge_index is int64 (little endian, values < 2^31), the odd 32-bit words
// (high halves) of the buffer are all zero. If int32, they are random values
// in [0, N) — all-zero across 64 samples is impossible in practice.
__global__ void detect_k(const int* __restrict__ edges, int* __restrict__ flag) {
    int t = threadIdx.x;            // 64 threads
    int v = edges[2 * t + 1];
    unsigned long long b = __ballot(v == 0);
    if (t == 0) flag[0] = (b == ~0ULL) ? 1 : 0;
}

__global__ void init_k(float* __restrict__ deg, int* __restrict__ cnt,
                       int* __restrict__ cursor, int n) {
    int i = blockIdx.x * 256 + threadIdx.x;
    if (i < n) { deg[i] = 1.0f; cnt[i] = 0; cursor[i] = 0; }
}

__global__ void convert_count_k(const void* __restrict__ edges, int E, const int* __restrict__ flag,
                                int* __restrict__ src32, int* __restrict__ dst32,
                                int* __restrict__ cnt, float* __restrict__ deg) {
    int e = blockIdx.x * 256 + threadIdx.x;
    if (e >= E) return;
    int s, d;
    if (flag[0]) {
        const long long* p = (const long long*)edges;
        s = (int)p[e]; d = (int)p[(size_t)E + e];
    } else {
        const int* p = (const int*)edges;
        s = p[e]; d = p[(size_t)E + e];
    }
    src32[e] = s; dst32[e] = d;
    atomicAdd(&cnt[d], 1);
    atomicAdd(&deg[d], 1.0f);
}

__global__ void rsqrt_k(float* __restrict__ dinv, int n) {
    int i = blockIdx.x * 256 + threadIdx.x;
    if (i < n) dinv[i] = rsqrtf(dinv[i]);   // deg >= 1 always (self loop)
}

// ---------------------------------------------------------------------------
// exclusive scan of cnt[] -> rowptr[] (3-kernel hierarchical scan, 1024/block)
__global__ __launch_bounds__(256) void scan1_k(const int* __restrict__ cnt,
                                               int* __restrict__ stmp,
                                               int* __restrict__ bsum, int n) {
    __shared__ int lds[256];
    int t = threadIdx.x, b = blockIdx.x;
    int base = b * 1024 + t * 4;
    int v0 = (base + 0 < n) ? cnt[base + 0] : 0;
    int v1 = (base + 1 < n) ? cnt[base + 1] : 0;
    int v2 = (base + 2 < n) ? cnt[base + 2] : 0;
    int v3 = (base + 3 < n) ? cnt[base + 3] : 0;
    int p0 = v0, p1 = p0 + v1, p2 = p1 + v2, p3 = p2 + v3;
    lds[t] = p3;
    __syncthreads();
    int own = p3;
    for (int o = 1; o < 256; o <<= 1) {
        int x = (t >= o) ? lds[t - o] : 0;
        __syncthreads();
        lds[t] += x;
        __syncthreads();
    }
    int excl = lds[t] - own;                 // exclusive prefix of this thread
    if (base + 0 < n) stmp[base + 0] = excl + p0;   // block-inclusive
    if (base + 1 < n) stmp[base + 1] = excl + p1;
    if (base + 2 < n) stmp[base + 2] = excl + p2;
    if (base + 3 < n) stmp[base + 3] = excl + p3;
    if (t == 255) bsum[b] = lds[255];
}

__global__ void scan2_k(int* __restrict__ bsum, int nb) {
    __shared__ int lds[128];
    int t = threadIdx.x;
    int v = (t < nb) ? bsum[t] : 0;
    lds[t] = v;
    __syncthreads();
    for (int o = 1; o < 128; o <<= 1) {
        int x = (t >= o) ? lds[t - o] : 0;
        __syncthreads();
        lds[t] += x;
        __syncthreads();
    }
    if (t < nb) bsum[t] = lds[t] - v;        // exclusive
}

__global__ void scan3_k(const int* __restrict__ cnt, const int* __restrict__ stmp,
                        const int* __restrict__ bsum, int* __restrict__ rowptr,
                        int n, int E) {
    int i = blockIdx.x * 256 + threadIdx.x;
    if (i < n) rowptr[i] = stmp[i] - cnt[i] + bsum[i >> 10];
    if (i == 0) rowptr[n] = E;
}

__global__ void fill_k(const int* __restrict__ src32, const int* __restrict__ dst32,
                       int* __restrict__ cursor, const int* __restrict__ rowptr,
                       const float* __restrict__ dinv,
                       int* __restrict__ csrs, float* __restrict__ csrn, int E) {
    int e = blockIdx.x * 256 + threadIdx.x;
    if (e >= E) return;
    int s = src32[e], d = dst32[e];
    int pos = atomicAdd(&cursor[d], 1);
    int slot = rowptr[d] + pos;
    csrs[slot] = s;
    csrn[slot] = dinv[s] * dinv[d];
}

// ---------------------------------------------------------------------------
// GEMM: Y[nrows x NCOL] = X[nrows x 128] @ W[128 x NCOL]   (fp32, vector ALU)
// 64-row tile, X-tile transposed in LDS (padded), W K-tiled 32 rows at a time.
template <int NCOL>
__global__ __launch_bounds__(256) void gemm_k(const float* __restrict__ X,
                                              const float* __restrict__ W,
                                              float* __restrict__ Y, int nrows) {
    constexpr int KDIM = 128;
    constexpr int TM = 64;
    constexpr int KT = 32;
    constexpr int CPT = NCOL / 16;           // cols per thread: 8 or 2
    __shared__ float xt[KDIM][TM + 4];       // transposed X tile, padded
    __shared__ float wt[KT][NCOL];

    const int t = threadIdx.x;
    const int ty = t >> 4, tx = t & 15;
    const int row0 = blockIdx.x * TM;

    const float4* X4 = (const float4*)X;
#pragma unroll
    for (int i = 0; i < 8; ++i) {
        int idx = i * 256 + t;               // 0..2047, coalesced
        int r = idx >> 5;                    // 32 float4 per row
        int k4 = idx & 31;
        int gr = row0 + r;
        if (gr > nrows - 1) gr = nrows - 1;
        float4 v = X4[(size_t)gr * 32 + k4];
        xt[k4 * 4 + 0][r] = v.x;
        xt[k4 * 4 + 1][r] = v.y;
        xt[k4 * 4 + 2][r] = v.z;
        xt[k4 * 4 + 3][r] = v.w;
    }

    float acc[4][CPT];
#pragma unroll
    for (int r = 0; r < 4; ++r)
#pragma unroll
        for (int c = 0; c < CPT; ++c) acc[r][c] = 0.0f;

    const float4* W4 = (const float4*)W;
    for (int kt = 0; kt < KDIM / KT; ++kt) {
        __syncthreads();                     // xt ready / wt no longer in use
        constexpr int F4 = KT * NCOL / 4;
#pragma unroll
        for (int i = 0; i < F4 / 256; ++i) {
            int idx = i * 256 + t;
            int r = idx / (NCOL / 4);
            int c4 = idx % (NCOL / 4);
            float4 v = W4[(size_t)(kt * KT + r) * (NCOL / 4) + c4];
            *(float4*)&wt[r][c4 * 4] = v;
        }
        __syncthreads();
#pragma unroll
        for (int k = 0; k < KT; ++k) {
            float4 a = *(const float4*)&xt[kt * KT + k][ty * 4];
            float av[4] = {a.x, a.y, a.z, a.w};
            float bv[CPT];
#pragma unroll
            for (int c = 0; c < CPT; ++c) bv[c] = wt[k][tx * CPT + c];
#pragma unroll
            for (int r = 0; r < 4; ++r)
#pragma unroll
                for (int c = 0; c < CPT; ++c)
                    acc[r][c] = fmaf(av[r], bv[c], acc[r][c]);
        }
    }

#pragma unroll
    for (int r = 0; r < 4; ++r) {
        int gr = row0 + ty * 4 + r;
        if (gr < nrows) {
#pragma unroll
            for (int c = 0; c < CPT; ++c)
                Y[(size_t)gr * NCOL + tx * CPT + c] = acc[r][c];
        }
    }
}

// ---------------------------------------------------------------------------
// CSR aggregation: out[i] = dinv[i]^2*H[i] + sum_e norm_e*H[src_e] + bias
// F4 = float4 per feature row (32 for D=128, 8 for D=32); 256/F4 nodes/block.
template <int F4>
__global__ __launch_bounds__(256) void agg_k(const float* __restrict__ H,
                                             const float* __restrict__ dinv,
                                             const int* __restrict__ rowptr,
                                             const int* __restrict__ csrs,
                                             const float* __restrict__ csrn,
                                             const float* __restrict__ bias,
                                             float* __restrict__ out, int n) {
    constexpr int GP = 256 / F4;
    int g = threadIdx.x / F4;
    int lane = threadIdx.x % F4;
    int node = blockIdx.x * GP + g;
    if (node >= n) return;

    const float4* H4 = (const float4*)H;
    float di = dinv[node];
    float w0 = di * di;
    float4 v = H4[(size_t)node * F4 + lane];
    float ax = v.x * w0, ay = v.y * w0, az = v.z * w0, aw = v.w * w0;

    int s = rowptr[node], e = rowptr[node + 1];
    for (; s < e; ++s) {
        int src = csrs[s];
        float w = csrn[s];
        float4 hv = H4[(size_t)src * F4 + lane];
        ax = fmaf(w, hv.x, ax);
        ay = fmaf(w, hv.y, ay);
        az = fmaf(w, hv.z, az);
        aw = fmaf(w, hv.w, aw);
    }
    float4 b4 = ((const float4*)bias)[lane];
    float4 o = make_float4(ax + b4.x, ay + b4.y, az + b4.z, aw + b4.w);
    ((float4*)out)[(size_t)node * F4 + lane] = o;
}

// ---------------------------------------------------------------------------
// BatchNorm (training stats over node axis) + ReLU
__global__ void zstats_k(float* __restrict__ stats) {
    stats[threadIdx.x] = 0.0f;               // 256 threads: sum[128], sumsq[128]
}

__global__ __launch_bounds__(256) void bnstats_k(const float* __restrict__ X,
                                                 float* __restrict__ stats, int n) {
    __shared__ float ls[256], ls2[256];
    int t = threadIdx.x;
    int col = t & 127;
    int half = t >> 7;
    float s = 0.0f, s2 = 0.0f;
    for (int r = blockIdx.x * 2 + half; r < n; r += gridDim.x * 2) {
        float v = X[(size_t)r * 128 + col];
        s += v;
        s2 = fmaf(v, v, s2);
    }
    ls[t] = s; ls2[t] = s2;
    __syncthreads();
    if (t < 128) {
        s = ls[t] + ls[t + 128];
        s2 = ls2[t] + ls2[t + 128];
        atomicAdd(&stats[col], s);
        atomicAdd(&stats[128 + col], s2);
    }
}

__global__ void bnapply_k(float* __restrict__ X, const float* __restrict__ stats,
                          const float* __restrict__ g, const float* __restrict__ be, int n) {
    size_t i = (size_t)blockIdx.x * 256 + threadIdx.x;   // index over float4s
    size_t tot = (size_t)n * 32;
    if (i >= tot) return;
    int c4 = (int)(i & 31);
    float4 v = ((const float4*)X)[i];
    float vv[4] = {v.x, v.y, v.z, v.w};
    float rr[4];
    float inv = 1.0f / (float)n;
#pragma unroll
    for (int j = 0; j < 4; ++j) {
        int c = c4 * 4 + j;
        float m = stats[c] * inv;
        float var = stats[128 + c] * inv - m * m;
        float sc = rsqrtf(var + BN_EPS) * g[c];
        float y = (vv[j] - m) * sc + be[c];
        rr[j] = fmaxf(y, 0.0f);
    }
    ((float4*)X)[i] = make_float4(rr[0], rr[1], rr[2], rr[3]);
}

// ---------------------------------------------------------------------------
// log_softmax over rows of 32 (one 32-lane group per row)
__global__ __launch_bounds__(256) void lsm_k(const float* __restrict__ X,
                                             float* __restrict__ out, int n) {
    int t = threadIdx.x;
    int g = t >> 5;
    int lane = t & 31;
    int row = blockIdx.x * 8 + g;
    if (row >= n) return;
    float v = X[(size_t)row * 32 + lane];
    float m = v;
    for (int o = 16; o; o >>= 1) m = fmaxf(m, __shfl_xor(m, o, 32));
    float ex = __expf(v - m);
    float s = ex;
    for (int o = 16; o; o >>= 1) s += __shfl_xor(s, o, 32);
    out[(size_t)row * 32 + lane] = v - m - logf(s);
}

// ---------------------------------------------------------------------------
extern "C" void kernel_launch(void* const* d_in, const int* in_sizes, int n_in,
                              void* d_out, int out_size, void* d_ws, size_t ws_size,
                              hipStream_t stream) {
    const int N = in_sizes[0] / 128;
    const int E = in_sizes[1] / 2;

    const float* x   = (const float*)d_in[0];
    const void*  edg = d_in[1];
    const float* W0  = (const float*)d_in[2];
    const float* b0  = (const float*)d_in[3];
    const float* g0  = (const float*)d_in[4];
    const float* be0 = (const float*)d_in[5];
    const float* W1  = (const float*)d_in[6];
    const float* b1  = (const float*)d_in[7];
    const float* g1  = (const float*)d_in[8];
    const float* be1 = (const float*)d_in[9];
    const float* W2  = (const float*)d_in[10];
    const float* b2  = (const float*)d_in[11];
    float* out = (float*)d_out;

    char* ws = (char*)d_ws;
    size_t off = 0;
    auto alloc = [&](size_t bytes) {
        char* p = ws + off;
        off = (off + bytes + 255) & ~(size_t)255;
        return p;
    };
    int*   flag   = (int*)  alloc(16);
    float* dinv   = (float*)alloc((size_t)N * 4);        // deg, then rsqrt in place
    int*   cnt    = (int*)  alloc((size_t)N * 4);
    int*   cursor = (int*)  alloc((size_t)N * 4);
    int*   src32  = (int*)  alloc((size_t)E * 4);
    int*   dst32  = (int*)  alloc((size_t)E * 4);
    int*   rowptr = (int*)  alloc((size_t)(N + 1) * 4);
    int*   stmp   = (int*)  alloc((size_t)N * 4);
    int*   bsum   = (int*)  alloc(512);
    int*   csrs   = (int*)  alloc((size_t)E * 4);
    float* csrn   = (float*)alloc((size_t)E * 4);
    float* h      = (float*)alloc((size_t)N * 128 * 4);
    float* agg    = (float*)alloc((size_t)N * 128 * 4);
    float* stats  = (float*)alloc(256 * 4);
    (void)ws_size; (void)n_in; (void)out_size;

    dim3 B(256);
    int gN  = (N + 255) / 256;
    int gE  = (E + 255) / 256;
    int nb  = (N + 1023) / 1024;
    int gGm = (N + 63) / 64;
    int gA32 = (N + 7) / 8;
    int gA8  = (N + 31) / 32;
    int gBN  = (int)(((size_t)N * 32 + 255) / 256);
    int gLSM = (N + 7) / 8;

    // graph construction (shared across the 3 conv layers)
    detect_k<<<dim3(1), dim3(64), 0, stream>>>((const int*)edg, flag);
    init_k<<<gN, B, 0, stream>>>(dinv, cnt, cursor, N);
    convert_count_k<<<gE, B, 0, stream>>>(edg, E, flag, src32, dst32, cnt, dinv);
    rsqrt_k<<<gN, B, 0, stream>>>(dinv, N);
    scan1_k<<<nb, B, 0, stream>>>(cnt, stmp, bsum, N);
    scan2_k<<<dim3(1), dim3(128), 0, stream>>>(bsum, nb);
    scan3_k<<<gN, B, 0, stream>>>(cnt, stmp, bsum, rowptr, N, E);
    fill_k<<<gE, B, 0, stream>>>(src32, dst32, cursor, rowptr, dinv, csrs, csrn, E);

    // layer 0: x(N,128) -> agg(N,128), BN+ReLU in place
    gemm_k<128><<<gGm, B, 0, stream>>>(x, W0, h, N);
    agg_k<32><<<gA32, B, 0, stream>>>(h, dinv, rowptr, csrs, csrn, b0, agg, N);
    zstats_k<<<dim3(1), B, 0, stream>>>(stats);
    bnstats_k<<<dim3(512), B, 0, stream>>>(agg, stats, N);
    bnapply_k<<<gBN, B, 0, stream>>>(agg, stats, g0, be0, N);

    // layer 1
    gemm_k<128><<<gGm, B, 0, stream>>>(agg, W1, h, N);
    agg_k<32><<<gA32, B, 0, stream>>>(h, dinv, rowptr, csrs, csrn, b1, agg, N);
    zstats_k<<<dim3(1), B, 0, stream>>>(stats);
    bnstats_k<<<dim3(512), B, 0, stream>>>(agg, stats, N);
    bnapply_k<<<gBN, B, 0, stream>>>(agg, stats, g1, be1, N);

    // layer 2: (N,128) -> (N,32), then log_softmax -> d_out
    gemm_k<32><<<gGm, B, 0, stream>>>(agg, W2, h, N);
    agg_k<8><<<gA8, B, 0, stream>>>(h, dinv, rowptr, csrs, csrn, b2, agg, N);
    lsm_k<<<gLSM, B, 0, stream>>>(agg, out, N);
}

// Round 8
// 753.939 us; speedup vs baseline: 1.1871x; 1.1871x over previous
//
#include <hip/hip_runtime.h>
#include <hip/hip_bf16.h>
#include <cstdint>
#include <cstddef>

#define BN_EPS 1e-5f

// ---------------------------------------------------------------------------
// int64-vs-int32 edge dtype detection.
// If edge_index is int64 (little endian, values < 2^31), the odd 32-bit words
// (high halves) of the buffer are all zero. If int32, they are random values
// in [0, N) — all-zero across 64 samples is impossible in practice.
__global__ void detect_k(const int* __restrict__ edges, int* __restrict__ flag) {
    int t = threadIdx.x;            // 64 threads
    int v = edges[2 * t + 1];
    unsigned long long b = __ballot(v == 0);
    if (t == 0) flag[0] = (b == ~0ULL) ? 1 : 0;
}

// zero histogram + both BN stats buffers (1024 floats incl. padding)
__global__ void init_k(int* __restrict__ cnt, float* __restrict__ stats, int n) {
    int i = blockIdx.x * 256 + threadIdx.x;
    if (i < n) cnt[i] = 0;
    if (i < 1024) stats[i] = 0.0f;
}

// One atomic per edge; its return value doubles as the within-dst ordinal,
// so fill_k below needs no atomics at all. deg is derived later as cnt+1.
__global__ void convert_count_k(const void* __restrict__ edges, int E, const int* __restrict__ flag,
                                int* __restrict__ src32, int* __restrict__ dst32,
                                int* __restrict__ ord, int* __restrict__ cnt) {
    int e = blockIdx.x * 256 + threadIdx.x;
    if (e >= E) return;
    int s, d;
    if (flag[0]) {
        const long long* p = (const long long*)edges;
        s = (int)p[e]; d = (int)p[(size_t)E + e];
    } else {
        const int* p = (const int*)edges;
        s = p[e]; d = p[(size_t)E + e];
    }
    src32[e] = s; dst32[e] = d;
    ord[e] = atomicAdd(&cnt[d], 1);
}

// ---------------------------------------------------------------------------
// exclusive scan of cnt[] -> rowptr[] (3-kernel hierarchical scan, 1024/block)
__global__ __launch_bounds__(256) void scan1_k(const int* __restrict__ cnt,
                                               int* __restrict__ stmp,
                                               int* __restrict__ bsum, int n) {
    __shared__ int lds[256];
    int t = threadIdx.x, b = blockIdx.x;
    int base = b * 1024 + t * 4;
    int v0 = (base + 0 < n) ? cnt[base + 0] : 0;
    int v1 = (base + 1 < n) ? cnt[base + 1] : 0;
    int v2 = (base + 2 < n) ? cnt[base + 2] : 0;
    int v3 = (base + 3 < n) ? cnt[base + 3] : 0;
    int p0 = v0, p1 = p0 + v1, p2 = p1 + v2, p3 = p2 + v3;
    lds[t] = p3;
    __syncthreads();
    int own = p3;
    for (int o = 1; o < 256; o <<= 1) {
        int x = (t >= o) ? lds[t - o] : 0;
        __syncthreads();
        lds[t] += x;
        __syncthreads();
    }
    int excl = lds[t] - own;                 // exclusive prefix of this thread
    if (base + 0 < n) stmp[base + 0] = excl + p0;   // block-inclusive
    if (base + 1 < n) stmp[base + 1] = excl + p1;
    if (base + 2 < n) stmp[base + 2] = excl + p2;
    if (base + 3 < n) stmp[base + 3] = excl + p3;
    if (t == 255) bsum[b] = lds[255];
}

__global__ void scan2_k(int* __restrict__ bsum, int nb) {
    __shared__ int lds[128];
    int t = threadIdx.x;
    int v = (t < nb) ? bsum[t] : 0;
    lds[t] = v;
    __syncthreads();
    for (int o = 1; o < 128; o <<= 1) {
        int x = (t >= o) ? lds[t - o] : 0;
        __syncthreads();
        lds[t] += x;
        __syncthreads();
    }
    if (t < nb) bsum[t] = lds[t] - v;        // exclusive
}

// rowptr from scan pieces; also dinv = rsqrt(deg) with deg = cnt+1 (self loop)
__global__ void scan3_k(const int* __restrict__ cnt, const int* __restrict__ stmp,
                        const int* __restrict__ bsum, int* __restrict__ rowptr,
                        float* __restrict__ dinv, int n, int E) {
    int i = blockIdx.x * 256 + threadIdx.x;
    if (i < n) {
        rowptr[i] = stmp[i] - cnt[i] + bsum[i >> 10];
        dinv[i] = rsqrtf((float)(cnt[i] + 1));
    }
    if (i == 0) rowptr[n] = E;
}

// atomic-free fill: slot = rowptr[dst] + ord; packed {src, norm} per edge.
__global__ void fill_k(const int* __restrict__ src32, const int* __restrict__ dst32,
                       const int* __restrict__ ord, const int* __restrict__ rowptr,
                       const float* __restrict__ dinv,
                       int2* __restrict__ csre, int E) {
    int e = blockIdx.x * 256 + threadIdx.x;
    if (e >= E) return;
    int s = src32[e], d = dst32[e];
    int slot = rowptr[d] + ord[e];
    float w = dinv[s] * dinv[d];
    csre[slot] = make_int2(s, __float_as_int(w));
}

// ---------------------------------------------------------------------------
// GEMM: Y[nrows x NCOL] = f(X)[nrows x 128] @ W[128 x NCOL]  (fp32, vector ALU)
// 64-row tile, X-tile transposed in LDS (padded), W K-tiled 32 rows at a time.
// Thread tx owns columns {tx + 16*c}: lane LDS reads are stride-4B ->
// conflict-free. FUSE_BN applies f = relu(bn(.)) during X staging:
// (x-m)*rsqrt(var+eps)*g + be == x*sc + sh with sh = be - m*sc; each thread's
// staged feature columns (t&31)*4+j are loop-invariant -> sc/sh in registers.
template <int NCOL, bool FUSE_BN>
__global__ __launch_bounds__(256) void gemm_k(const float* __restrict__ X,
                                              const float* __restrict__ W,
                                              float* __restrict__ Y, int nrows,
                                              const float* __restrict__ stats,
                                              const float* __restrict__ gam,
                                              const float* __restrict__ bet) {
    constexpr int KDIM = 128;
    constexpr int TM = 64;
    constexpr int KT = 32;
    constexpr int CPT = NCOL / 16;           // cols per thread: 8 or 2
    __shared__ float xt[KDIM][TM + 4];       // transposed X tile, padded
    __shared__ float wt[KT][NCOL];

    const int t = threadIdx.x;
    const int ty = t >> 4, tx = t & 15;
    const int row0 = blockIdx.x * TM;

    float sc[4], sh[4];
    if (FUSE_BN) {
        float invn = 1.0f / (float)nrows;
        int k4c = (t & 31) * 4;
#pragma unroll
        for (int j = 0; j < 4; ++j) {
            int c = k4c + j;
            float m = stats[c] * invn;
            float var = stats[128 + c] * invn - m * m;
            float s = rsqrtf(var + BN_EPS) * gam[c];
            sc[j] = s;
            sh[j] = bet[c] - m * s;
        }
    }

    const float4* X4 = (const float4*)X;
#pragma unroll
    for (int i = 0; i < 8; ++i) {
        int idx = i * 256 + t;               // 0..2047, coalesced
        int r = idx >> 5;                    // 32 float4 per row
        int k4 = idx & 31;                   // == t & 31 (invariant)
        int gr = row0 + r;
        if (gr > nrows - 1) gr = nrows - 1;
        float4 v = X4[(size_t)gr * 32 + k4];
        if (FUSE_BN) {
            v.x = fmaxf(fmaf(v.x, sc[0], sh[0]), 0.0f);
            v.y = fmaxf(fmaf(v.y, sc[1], sh[1]), 0.0f);
            v.z = fmaxf(fmaf(v.z, sc[2], sh[2]), 0.0f);
            v.w = fmaxf(fmaf(v.w, sc[3], sh[3]), 0.0f);
        }
        xt[k4 * 4 + 0][r] = v.x;
        xt[k4 * 4 + 1][r] = v.y;
        xt[k4 * 4 + 2][r] = v.z;
        xt[k4 * 4 + 3][r] = v.w;
    }

    float acc[4][CPT];
#pragma unroll
    for (int r = 0; r < 4; ++r)
#pragma unroll
        for (int c = 0; c < CPT; ++c) acc[r][c] = 0.0f;

    const float4* W4 = (const float4*)W;
    for (int kt = 0; kt < KDIM / KT; ++kt) {
        __syncthreads();                     // xt ready / wt no longer in use
        constexpr int F4 = KT * NCOL / 4;
#pragma unroll
        for (int i = 0; i < F4 / 256; ++i) {
            int idx = i * 256 + t;
            int r = idx / (NCOL / 4);
            int c4 = idx % (NCOL / 4);
            float4 v = W4[(size_t)(kt * KT + r) * (NCOL / 4) + c4];
            *(float4*)&wt[r][c4 * 4] = v;
        }
        __syncthreads();
#pragma unroll
        for (int k = 0; k < KT; ++k) {
            float4 a = *(const float4*)&xt[kt * KT + k][ty * 4];
            float av[4] = {a.x, a.y, a.z, a.w};
            float bv[CPT];
#pragma unroll
            for (int c = 0; c < CPT; ++c) bv[c] = wt[k][tx + 16 * c];
#pragma unroll
            for (int r = 0; r < 4; ++r)
#pragma unroll
                for (int c = 0; c < CPT; ++c)
                    acc[r][c] = fmaf(av[r], bv[c], acc[r][c]);
        }
    }

#pragma unroll
    for (int r = 0; r < 4; ++r) {
        int gr = row0 + ty * 4 + r;
        if (gr < nrows) {
#pragma unroll
            for (int c = 0; c < CPT; ++c)
                Y[(size_t)gr * NCOL + tx + 16 * c] = acc[r][c];
        }
    }
}

// ---------------------------------------------------------------------------
// CSR aggregation: out[i] = dinv[i]^2*H[i] + sum_e norm_e*H[src_e] + bias
// F4 = float4 per feature row (32 for D=128, 8 for D=32); 256/F4 nodes/block.
// Edge loop unrolled x2: two independent gathers in flight per iteration.
template <int F4>
__global__ __launch_bounds__(256) void agg_k(const float* __restrict__ H,
                                             const float* __restrict__ dinv,
                                             const int* __restrict__ rowptr,
                                             const int2* __restrict__ csre,
                                             const float* __restrict__ bias,
                                             float* __restrict__ out, int n) {
    constexpr int GP = 256 / F4;
    int g = threadIdx.x / F4;
    int lane = threadIdx.x % F4;
    int node = blockIdx.x * GP + g;
    if (node >= n) return;

    const float4* H4 = (const float4*)H;
    float di = dinv[node];
    float w0 = di * di;
    float4 v = H4[(size_t)node * F4 + lane];
    float ax = v.x * w0, ay = v.y * w0, az = v.z * w0, aw = v.w * w0;

    int s = rowptr[node], e = rowptr[node + 1];
    for (; s + 1 < e; s += 2) {
        int2 ev0 = csre[s];
        int2 ev1 = csre[s + 1];
        float4 h0 = H4[(size_t)ev0.x * F4 + lane];
        float4 h1 = H4[(size_t)ev1.x * F4 + lane];
        float wa = __int_as_float(ev0.y);
        float wb = __int_as_float(ev1.y);
        ax = fmaf(wa, h0.x, ax);
        ay = fmaf(wa, h0.y, ay);
        az = fmaf(wa, h0.z, az);
        aw = fmaf(wa, h0.w, aw);
        ax = fmaf(wb, h1.x, ax);
        ay = fmaf(wb, h1.y, ay);
        az = fmaf(wb, h1.z, az);
        aw = fmaf(wb, h1.w, aw);
    }
    if (s < e) {
        int2 ev = csre[s];
        float w = __int_as_float(ev.y);
        float4 hv = H4[(size_t)ev.x * F4 + lane];
        ax = fmaf(w, hv.x, ax);
        ay = fmaf(w, hv.y, ay);
        az = fmaf(w, hv.z, az);
        aw = fmaf(w, hv.w, aw);
    }
    float4 b4 = ((const float4*)bias)[lane];
    float4 o = make_float4(ax + b4.x, ay + b4.y, az + b4.z, aw + b4.w);
    ((float4*)out)[(size_t)node * F4 + lane] = o;
}

// ---------------------------------------------------------------------------
// BatchNorm stats over node axis (sum, sumsq per column) -> stats[256]
__global__ __launch_bounds__(256) void bnstats_k(const float* __restrict__ X,
                                                 float* __restrict__ stats, int n) {
    __shared__ float ls[256], ls2[256];
    int t = threadIdx.x;
    int col = t & 127;
    int half = t >> 7;
    float s = 0.0f, s2 = 0.0f;
    for (int r = blockIdx.x * 2 + half; r < n; r += gridDim.x * 2) {
        float v = X[(size_t)r * 128 + col];
        s += v;
        s2 = fmaf(v, v, s2);
    }
    ls[t] = s; ls2[t] = s2;
    __syncthreads();
    if (t < 128) {
        s = ls[t] + ls[t + 128];
        s2 = ls2[t] + ls2[t + 128];
        atomicAdd(&stats[col], s);
        atomicAdd(&stats[128 + col], s2);
    }
}

// ---------------------------------------------------------------------------
// log_softmax over rows of 32 (one 32-lane group per row)
__global__ __launch_bounds__(256) void lsm_k(const float* __restrict__ X,
                                             float* __restrict__ out, int n) {
    int t = threadIdx.x;
    int g = t >> 5;
    int lane = t & 31;
    int row = blockIdx.x * 8 + g;
    if (row >= n) return;
    float v = X[(size_t)row * 32 + lane];
    float m = v;
    for (int o = 16; o; o >>= 1) m = fmaxf(m, __shfl_xor(m, o, 32));
    float ex = __expf(v - m);
    float s = ex;
    for (int o = 16; o; o >>= 1) s += __shfl_xor(s, o, 32);
    out[(size_t)row * 32 + lane] = v - m - logf(s);
}

// ---------------------------------------------------------------------------
extern "C" void kernel_launch(void* const* d_in, const int* in_sizes, int n_in,
                              void* d_out, int out_size, void* d_ws, size_t ws_size,
                              hipStream_t stream) {
    const int N = in_sizes[0] / 128;
    const int E = in_sizes[1] / 2;

    const float* x   = (const float*)d_in[0];
    const void*  edg = d_in[1];
    const float* W0  = (const float*)d_in[2];
    const float* b0  = (const float*)d_in[3];
    const float* g0  = (const float*)d_in[4];
    const float* be0 = (const float*)d_in[5];
    const float* W1  = (const float*)d_in[6];
    const float* b1  = (const float*)d_in[7];
    const float* g1  = (const float*)d_in[8];
    const float* be1 = (const float*)d_in[9];
    const float* W2  = (const float*)d_in[10];
    const float* b2  = (const float*)d_in[11];
    float* out = (float*)d_out;

    char* ws = (char*)d_ws;
    size_t off = 0;
    auto alloc = [&](size_t bytes) {
        char* p = ws + off;
        off = (off + bytes + 255) & ~(size_t)255;
        return p;
    };
    int*   flag   = (int*)  alloc(16);
    float* dinv   = (float*)alloc((size_t)N * 4);
    int*   cnt    = (int*)  alloc((size_t)N * 4);
    int*   src32  = (int*)  alloc((size_t)E * 4);
    int*   dst32  = (int*)  alloc((size_t)E * 4);
    int*   ord    = (int*)  alloc((size_t)E * 4);
    int*   rowptr = (int*)  alloc((size_t)(N + 1) * 4);
    int*   stmp   = (int*)  alloc((size_t)N * 4);
    int*   bsum   = (int*)  alloc(512);
    int2*  csre   = (int2*) alloc((size_t)E * 8);
    float* h      = (float*)alloc((size_t)N * 128 * 4);
    float* agg    = (float*)alloc((size_t)N * 128 * 4);
    float* stats  = (float*)alloc(1024 * 4);   // [sum0|sq0|sum1|sq1] x 128
    float* stats0 = stats;
    float* stats1 = stats + 256;
    (void)ws_size; (void)n_in; (void)out_size;

    dim3 B(256);
    int gN  = (N + 255) / 256;
    int gE  = (E + 255) / 256;
    int nb  = (N + 1023) / 1024;
    int gGm = (N + 63) / 64;
    int gA32 = (N + 7) / 8;
    int gA8  = (N + 31) / 32;
    int gLSM = (N + 7) / 8;

    // graph construction (shared across the 3 conv layers)
    detect_k<<<dim3(1), dim3(64), 0, stream>>>((const int*)edg, flag);
    init_k<<<gN, B, 0, stream>>>(cnt, stats, N);
    convert_count_k<<<gE, B, 0, stream>>>(edg, E, flag, src32, dst32, ord, cnt);
    scan1_k<<<nb, B, 0, stream>>>(cnt, stmp, bsum, N);
    scan2_k<<<dim3(1), dim3(128), 0, stream>>>(bsum, nb);
    scan3_k<<<gN, B, 0, stream>>>(cnt, stmp, bsum, rowptr, dinv, N, E);
    fill_k<<<gE, B, 0, stream>>>(src32, dst32, ord, rowptr, dinv, csre, E);

    // layer 0: h = x@W0; agg0 = A_hat h + b0; stats0 over agg0
    gemm_k<128, false><<<gGm, B, 0, stream>>>(x, W0, h, N, nullptr, nullptr, nullptr);
    agg_k<32><<<gA32, B, 0, stream>>>(h, dinv, rowptr, csre, b0, agg, N);
    bnstats_k<<<dim3(512), B, 0, stream>>>(agg, stats0, N);

    // layer 1: h = relu(bn0(agg0))@W1 (BN fused in staging); agg1; stats1
    gemm_k<128, true><<<gGm, B, 0, stream>>>(agg, W1, h, N, stats0, g0, be0);
    agg_k<32><<<gA32, B, 0, stream>>>(h, dinv, rowptr, csre, b1, agg, N);
    bnstats_k<<<dim3(512), B, 0, stream>>>(agg, stats1, N);

    // layer 2: h = relu(bn1(agg1))@W2; agg2 (N,32); log_softmax -> d_out
    gemm_k<32, true><<<gGm, B, 0, stream>>>(agg, W2, h, N, stats1, g1, be1);
    agg_k<8><<<gA8, B, 0, stream>>>(h, dinv, rowptr, csre, b2, agg, N);
    lsm_k<<<gLSM, B, 0, stream>>>(agg, out, N);
}

// Round 9
// 753.251 us; speedup vs baseline: 1.1882x; 1.0009x over previous
//
#include <hip/hip_runtime.h>
#include <hip/hip_bf16.h>
#include <cstdint>
#include <cstddef>

#define BN_EPS 1e-5f

// ---------------------------------------------------------------------------
// int64-vs-int32 edge dtype detection.
// If edge_index is int64 (little endian, values < 2^31), the odd 32-bit words
// (high halves) of the buffer are all zero. If int32, they are random values
// in [0, N) — all-zero across 64 samples is impossible in practice.
__global__ void detect_k(const int* __restrict__ edges, int* __restrict__ flag) {
    int t = threadIdx.x;            // 64 threads
    int v = edges[2 * t + 1];
    unsigned long long b = __ballot(v == 0);
    if (t == 0) flag[0] = (b == ~0ULL) ? 1 : 0;
}

// zero histogram + both BN stats buffers (1024 floats incl. padding)
__global__ void init_k(int* __restrict__ cnt, float* __restrict__ stats, int n) {
    int i = blockIdx.x * 256 + threadIdx.x;
    if (i < n) cnt[i] = 0;
    if (i < 1024) stats[i] = 0.0f;
}

// One atomic per edge; its return value doubles as the within-dst ordinal,
// so fill_k below needs no atomics at all. deg is derived later as cnt+1.
__global__ void convert_count_k(const void* __restrict__ edges, int E, const int* __restrict__ flag,
                                int* __restrict__ src32, int* __restrict__ dst32,
                                int* __restrict__ ord, int* __restrict__ cnt) {
    int e = blockIdx.x * 256 + threadIdx.x;
    if (e >= E) return;
    int s, d;
    if (flag[0]) {
        const long long* p = (const long long*)edges;
        s = (int)p[e]; d = (int)p[(size_t)E + e];
    } else {
        const int* p = (const int*)edges;
        s = p[e]; d = p[(size_t)E + e];
    }
    src32[e] = s; dst32[e] = d;
    ord[e] = atomicAdd(&cnt[d], 1);
}

// ---------------------------------------------------------------------------
// exclusive scan of cnt[] -> rowptr[] (3-kernel hierarchical scan, 1024/block)
__global__ __launch_bounds__(256) void scan1_k(const int* __restrict__ cnt,
                                               int* __restrict__ stmp,
                                               int* __restrict__ bsum, int n) {
    __shared__ int lds[256];
    int t = threadIdx.x, b = blockIdx.x;
    int base = b * 1024 + t * 4;
    int v0 = (base + 0 < n) ? cnt[base + 0] : 0;
    int v1 = (base + 1 < n) ? cnt[base + 1] : 0;
    int v2 = (base + 2 < n) ? cnt[base + 2] : 0;
    int v3 = (base + 3 < n) ? cnt[base + 3] : 0;
    int p0 = v0, p1 = p0 + v1, p2 = p1 + v2, p3 = p2 + v3;
    lds[t] = p3;
    __syncthreads();
    int own = p3;
    for (int o = 1; o < 256; o <<= 1) {
        int x = (t >= o) ? lds[t - o] : 0;
        __syncthreads();
        lds[t] += x;
        __syncthreads();
    }
    int excl = lds[t] - own;                 // exclusive prefix of this thread
    if (base + 0 < n) stmp[base + 0] = excl + p0;   // block-inclusive
    if (base + 1 < n) stmp[base + 1] = excl + p1;
    if (base + 2 < n) stmp[base + 2] = excl + p2;
    if (base + 3 < n) stmp[base + 3] = excl + p3;
    if (t == 255) bsum[b] = lds[255];
}

__global__ void scan2_k(int* __restrict__ bsum, int nb) {
    __shared__ int lds[128];
    int t = threadIdx.x;
    int v = (t < nb) ? bsum[t] : 0;
    lds[t] = v;
    __syncthreads();
    for (int o = 1; o < 128; o <<= 1) {
        int x = (t >= o) ? lds[t - o] : 0;
        __syncthreads();
        lds[t] += x;
        __syncthreads();
    }
    if (t < nb) bsum[t] = lds[t] - v;        // exclusive
}

// rowptr from scan pieces; also dinv = rsqrt(deg) with deg = cnt+1 (self loop)
__global__ void scan3_k(const int* __restrict__ cnt, const int* __restrict__ stmp,
                        const int* __restrict__ bsum, int* __restrict__ rowptr,
                        float* __restrict__ dinv, int n, int E) {
    int i = blockIdx.x * 256 + threadIdx.x;
    if (i < n) {
        rowptr[i] = stmp[i] - cnt[i] + bsum[i >> 10];
        dinv[i] = rsqrtf((float)(cnt[i] + 1));
    }
    if (i == 0) rowptr[n] = E;
}

// atomic-free fill: slot = rowptr[dst] + ord; packed {src, norm} per edge.
__global__ void fill_k(const int* __restrict__ src32, const int* __restrict__ dst32,
                       const int* __restrict__ ord, const int* __restrict__ rowptr,
                       const float* __restrict__ dinv,
                       int2* __restrict__ csre, int E) {
    int e = blockIdx.x * 256 + threadIdx.x;
    if (e >= E) return;
    int s = src32[e], d = dst32[e];
    int slot = rowptr[d] + ord[e];
    float w = dinv[s] * dinv[d];
    csre[slot] = make_int2(s, __float_as_int(w));
}

// ---------------------------------------------------------------------------
// GEMM: Y[nrows x NCOL] = f(X)[nrows x 128] @ W[128 x NCOL]  (fp32, vector ALU)
// 64-row tile, X-tile transposed in LDS (padded), W K-tiled 32 rows at a time.
// Thread tx owns columns {tx + 16*c}: lane LDS reads are stride-4B ->
// conflict-free. FUSE_BN applies f = relu(bn(.)) during X staging:
// (x-m)*rsqrt(var+eps)*g + be == x*sc + sh with sh = be - m*sc; each thread's
// staged feature columns (t&31)*4+j are loop-invariant -> sc/sh in registers.
template <int NCOL, bool FUSE_BN>
__global__ __launch_bounds__(256) void gemm_k(const float* __restrict__ X,
                                              const float* __restrict__ W,
                                              float* __restrict__ Y, int nrows,
                                              const float* __restrict__ stats,
                                              const float* __restrict__ gam,
                                              const float* __restrict__ bet) {
    constexpr int KDIM = 128;
    constexpr int TM = 64;
    constexpr int KT = 32;
    constexpr int CPT = NCOL / 16;           // cols per thread: 8 or 2
    __shared__ float xt[KDIM][TM + 4];       // transposed X tile, padded
    __shared__ float wt[KT][NCOL];

    const int t = threadIdx.x;
    const int ty = t >> 4, tx = t & 15;
    const int row0 = blockIdx.x * TM;

    float sc[4], sh[4];
    if (FUSE_BN) {
        float invn = 1.0f / (float)nrows;
        int k4c = (t & 31) * 4;
#pragma unroll
        for (int j = 0; j < 4; ++j) {
            int c = k4c + j;
            float m = stats[c] * invn;
            float var = stats[128 + c] * invn - m * m;
            float s = rsqrtf(var + BN_EPS) * gam[c];
            sc[j] = s;
            sh[j] = bet[c] - m * s;
        }
    }

    const float4* X4 = (const float4*)X;
#pragma unroll
    for (int i = 0; i < 8; ++i) {
        int idx = i * 256 + t;               // 0..2047, coalesced
        int r = idx >> 5;                    // 32 float4 per row
        int k4 = idx & 31;                   // == t & 31 (invariant)
        int gr = row0 + r;
        if (gr > nrows - 1) gr = nrows - 1;
        float4 v = X4[(size_t)gr * 32 + k4];
        if (FUSE_BN) {
            v.x = fmaxf(fmaf(v.x, sc[0], sh[0]), 0.0f);
            v.y = fmaxf(fmaf(v.y, sc[1], sh[1]), 0.0f);
            v.z = fmaxf(fmaf(v.z, sc[2], sh[2]), 0.0f);
            v.w = fmaxf(fmaf(v.w, sc[3], sh[3]), 0.0f);
        }
        xt[k4 * 4 + 0][r] = v.x;
        xt[k4 * 4 + 1][r] = v.y;
        xt[k4 * 4 + 2][r] = v.z;
        xt[k4 * 4 + 3][r] = v.w;
    }

    float acc[4][CPT];
#pragma unroll
    for (int r = 0; r < 4; ++r)
#pragma unroll
        for (int c = 0; c < CPT; ++c) acc[r][c] = 0.0f;

    const float4* W4 = (const float4*)W;
    for (int kt = 0; kt < KDIM / KT; ++kt) {
        __syncthreads();                     // xt ready / wt no longer in use
        constexpr int F4 = KT * NCOL / 4;
#pragma unroll
        for (int i = 0; i < F4 / 256; ++i) {
            int idx = i * 256 + t;
            int r = idx / (NCOL / 4);
            int c4 = idx % (NCOL / 4);
            float4 v = W4[(size_t)(kt * KT + r) * (NCOL / 4) + c4];
            *(float4*)&wt[r][c4 * 4] = v;
        }
        __syncthreads();
#pragma unroll
        for (int k = 0; k < KT; ++k) {
            float4 a = *(const float4*)&xt[kt * KT + k][ty * 4];
            float av[4] = {a.x, a.y, a.z, a.w};
            float bv[CPT];
#pragma unroll
            for (int c = 0; c < CPT; ++c) bv[c] = wt[k][tx + 16 * c];
#pragma unroll
            for (int r = 0; r < 4; ++r)
#pragma unroll
                for (int c = 0; c < CPT; ++c)
                    acc[r][c] = fmaf(av[r], bv[c], acc[r][c]);
        }
    }

#pragma unroll
    for (int r = 0; r < 4; ++r) {
        int gr = row0 + ty * 4 + r;
        if (gr < nrows) {
#pragma unroll
            for (int c = 0; c < CPT; ++c)
                Y[(size_t)gr * NCOL + tx + 16 * c] = acc[r][c];
        }
    }
}

// ---------------------------------------------------------------------------
// CSR aggregation: out[i] = dinv[i]^2*H[i] + sum_e norm_e*H[src_e] + bias
// F4 = float4 per feature row (32 for D=128, 8 for D=32); 256/F4 nodes/block.
// Edge loop unrolled x4: four independent gathers in flight per iteration
// (round-8 PMC: 48% peak BW, occupancy 77% -> latency knee, not BW asymptote;
// in-flight bytes/CU ~ waves x depth x 512B; 2->4 doubles it).
template <int F4>
__global__ __launch_bounds__(256) void agg_k(const float* __restrict__ H,
                                             const float* __restrict__ dinv,
                                             const int* __restrict__ rowptr,
                                             const int2* __restrict__ csre,
                                             const float* __restrict__ bias,
                                             float* __restrict__ out, int n) {
    constexpr int GP = 256 / F4;
    int g = threadIdx.x / F4;
    int lane = threadIdx.x % F4;
    int node = blockIdx.x * GP + g;
    if (node >= n) return;

    const float4* H4 = (const float4*)H;
    float di = dinv[node];
    float w0 = di * di;
    float4 v = H4[(size_t)node * F4 + lane];
    float ax = v.x * w0, ay = v.y * w0, az = v.z * w0, aw = v.w * w0;

    int s = rowptr[node], e = rowptr[node + 1];
    for (; s + 3 < e; s += 4) {
        int2 ev0 = csre[s];
        int2 ev1 = csre[s + 1];
        int2 ev2 = csre[s + 2];
        int2 ev3 = csre[s + 3];
        float4 h0 = H4[(size_t)ev0.x * F4 + lane];
        float4 h1 = H4[(size_t)ev1.x * F4 + lane];
        float4 h2 = H4[(size_t)ev2.x * F4 + lane];
        float4 h3 = H4[(size_t)ev3.x * F4 + lane];
        float wa = __int_as_float(ev0.y);
        float wb = __int_as_float(ev1.y);
        float wc = __int_as_float(ev2.y);
        float wd = __int_as_float(ev3.y);
        ax = fmaf(wa, h0.x, ax); ay = fmaf(wa, h0.y, ay);
        az = fmaf(wa, h0.z, az); aw = fmaf(wa, h0.w, aw);
        ax = fmaf(wb, h1.x, ax); ay = fmaf(wb, h1.y, ay);
        az = fmaf(wb, h1.z, az); aw = fmaf(wb, h1.w, aw);
        ax = fmaf(wc, h2.x, ax); ay = fmaf(wc, h2.y, ay);
        az = fmaf(wc, h2.z, az); aw = fmaf(wc, h2.w, aw);
        ax = fmaf(wd, h3.x, ax); ay = fmaf(wd, h3.y, ay);
        az = fmaf(wd, h3.z, az); aw = fmaf(wd, h3.w, aw);
    }
    for (; s < e; ++s) {
        int2 ev = csre[s];
        float w = __int_as_float(ev.y);
        float4 hv = H4[(size_t)ev.x * F4 + lane];
        ax = fmaf(w, hv.x, ax);
        ay = fmaf(w, hv.y, ay);
        az = fmaf(w, hv.z, az);
        aw = fmaf(w, hv.w, aw);
    }
    float4 b4 = ((const float4*)bias)[lane];
    float4 o = make_float4(ax + b4.x, ay + b4.y, az + b4.z, aw + b4.w);
    ((float4*)out)[(size_t)node * F4 + lane] = o;
}

// ---------------------------------------------------------------------------
// BatchNorm stats over node axis (sum, sumsq per column) -> stats[256]
__global__ __launch_bounds__(256) void bnstats_k(const float* __restrict__ X,
                                                 float* __restrict__ stats, int n) {
    __shared__ float ls[256], ls2[256];
    int t = threadIdx.x;
    int col = t & 127;
    int half = t >> 7;
    float s = 0.0f, s2 = 0.0f;
    for (int r = blockIdx.x * 2 + half; r < n; r += gridDim.x * 2) {
        float v = X[(size_t)r * 128 + col];
        s += v;
        s2 = fmaf(v, v, s2);
    }
    ls[t] = s; ls2[t] = s2;
    __syncthreads();
    if (t < 128) {
        s = ls[t] + ls[t + 128];
        s2 = ls2[t] + ls2[t + 128];
        atomicAdd(&stats[col], s);
        atomicAdd(&stats[128 + col], s2);
    }
}

// ---------------------------------------------------------------------------
// log_softmax over rows of 32 (one 32-lane group per row)
__global__ __launch_bounds__(256) void lsm_k(const float* __restrict__ X,
                                             float* __restrict__ out, int n) {
    int t = threadIdx.x;
    int g = t >> 5;
    int lane = t & 31;
    int row = blockIdx.x * 8 + g;
    if (row >= n) return;
    float v = X[(size_t)row * 32 + lane];
    float m = v;
    for (int o = 16; o; o >>= 1) m = fmaxf(m, __shfl_xor(m, o, 32));
    float ex = __expf(v - m);
    float s = ex;
    for (int o = 16; o; o >>= 1) s += __shfl_xor(s, o, 32);
    out[(size_t)row * 32 + lane] = v - m - logf(s);
}

// ---------------------------------------------------------------------------
extern "C" void kernel_launch(void* const* d_in, const int* in_sizes, int n_in,
                              void* d_out, int out_size, void* d_ws, size_t ws_size,
                              hipStream_t stream) {
    const int N = in_sizes[0] / 128;
    const int E = in_sizes[1] / 2;

    const float* x   = (const float*)d_in[0];
    const void*  edg = d_in[1];
    const float* W0  = (const float*)d_in[2];
    const float* b0  = (const float*)d_in[3];
    const float* g0  = (const float*)d_in[4];
    const float* be0 = (const float*)d_in[5];
    const float* W1  = (const float*)d_in[6];
    const float* b1  = (const float*)d_in[7];
    const float* g1  = (const float*)d_in[8];
    const float* be1 = (const float*)d_in[9];
    const float* W2  = (const float*)d_in[10];
    const float* b2  = (const float*)d_in[11];
    float* out = (float*)d_out;

    char* ws = (char*)d_ws;
    size_t off = 0;
    auto alloc = [&](size_t bytes) {
        char* p = ws + off;
        off = (off + bytes + 255) & ~(size_t)255;
        return p;
    };
    int*   flag   = (int*)  alloc(16);
    float* dinv   = (float*)alloc((size_t)N * 4);
    int*   cnt    = (int*)  alloc((size_t)N * 4);
    int*   src32  = (int*)  alloc((size_t)E * 4);
    int*   dst32  = (int*)  alloc((size_t)E * 4);
    int*   ord    = (int*)  alloc((size_t)E * 4);
    int*   rowptr = (int*)  alloc((size_t)(N + 1) * 4);
    int*   stmp   = (int*)  alloc((size_t)N * 4);
    int*   bsum   = (int*)  alloc(512);
    int2*  csre   = (int2*) alloc((size_t)E * 8);
    float* h      = (float*)alloc((size_t)N * 128 * 4);
    float* agg    = (float*)alloc((size_t)N * 128 * 4);
    float* stats  = (float*)alloc(1024 * 4);   // [sum0|sq0|sum1|sq1] x 128
    float* stats0 = stats;
    float* stats1 = stats + 256;
    (void)ws_size; (void)n_in; (void)out_size;

    dim3 B(256);
    int gN  = (N + 255) / 256;
    int gE  = (E + 255) / 256;
    int nb  = (N + 1023) / 1024;
    int gGm = (N + 63) / 64;
    int gA32 = (N + 7) / 8;
    int gA8  = (N + 31) / 32;
    int gLSM = (N + 7) / 8;

    // graph construction (shared across the 3 conv layers)
    detect_k<<<dim3(1), dim3(64), 0, stream>>>((const int*)edg, flag);
    init_k<<<gN, B, 0, stream>>>(cnt, stats, N);
    convert_count_k<<<gE, B, 0, stream>>>(edg, E, flag, src32, dst32, ord, cnt);
    scan1_k<<<nb, B, 0, stream>>>(cnt, stmp, bsum, N);
    scan2_k<<<dim3(1), dim3(128), 0, stream>>>(bsum, nb);
    scan3_k<<<gN, B, 0, stream>>>(cnt, stmp, bsum, rowptr, dinv, N, E);
    fill_k<<<gE, B, 0, stream>>>(src32, dst32, ord, rowptr, dinv, csre, E);

    // layer 0: h = x@W0; agg0 = A_hat h + b0; stats0 over agg0
    gemm_k<128, false><<<gGm, B, 0, stream>>>(x, W0, h, N, nullptr, nullptr, nullptr);
    agg_k<32><<<gA32, B, 0, stream>>>(h, dinv, rowptr, csre, b0, agg, N);
    bnstats_k<<<dim3(512), B, 0, stream>>>(agg, stats0, N);

    // layer 1: h = relu(bn0(agg0))@W1 (BN fused in staging); agg1; stats1
    gemm_k<128, true><<<gGm, B, 0, stream>>>(agg, W1, h, N, stats0, g0, be0);
    agg_k<32><<<gA32, B, 0, stream>>>(h, dinv, rowptr, csre, b1, agg, N);
    bnstats_k<<<dim3(512), B, 0, stream>>>(agg, stats1, N);

    // layer 2: h = relu(bn1(agg1))@W2; agg2 (N,32); log_softmax -> d_out
    gemm_k<32, true><<<gGm, B, 0, stream>>>(agg, W2, h, N, stats1, g1, be1);
    agg_k<8><<<gA8, B, 0, stream>>>(h, dinv, rowptr, csre, b2, agg, N);
    lsm_k<<<gLSM, B, 0, stream>>>(agg, out, N);
}

// Round 11
// 623.507 us; speedup vs baseline: 1.4354x; 1.2081x over previous
//
#include <hip/hip_runtime.h>
#include <hip/hip_bf16.h>
#include <cstdint>
#include <cstddef>

#define BN_EPS 1e-5f

// ---------------------------------------------------------------------------
// int64-vs-int32 edge dtype detection.
__global__ void detect_k(const int* __restrict__ edges, int* __restrict__ flag) {
    int t = threadIdx.x;            // 64 threads
    int v = edges[2 * t + 1];
    unsigned long long b = __ballot(v == 0);
    if (t == 0) flag[0] = (b == ~0ULL) ? 1 : 0;
}

// zero histogram + both BN stats buffers (1024 floats incl. padding)
__global__ void init_k(int* __restrict__ cnt, float* __restrict__ stats, int n) {
    int i = blockIdx.x * 256 + threadIdx.x;
    if (i < n) cnt[i] = 0;
    if (i < 1024) stats[i] = 0.0f;
}

// One atomic per edge; its return value doubles as the within-dst ordinal,
// so fill_k below needs no atomics at all. deg is derived later as cnt+1.
__global__ void convert_count_k(const void* __restrict__ edges, int E, const int* __restrict__ flag,
                                int* __restrict__ src32, int* __restrict__ dst32,
                                int* __restrict__ ord, int* __restrict__ cnt) {
    int e = blockIdx.x * 256 + threadIdx.x;
    if (e >= E) return;
    int s, d;
    if (flag[0]) {
        const long long* p = (const long long*)edges;
        s = (int)p[e]; d = (int)p[(size_t)E + e];
    } else {
        const int* p = (const int*)edges;
        s = p[e]; d = p[(size_t)E + e];
    }
    src32[e] = s; dst32[e] = d;
    ord[e] = atomicAdd(&cnt[d], 1);
}

// ---------------------------------------------------------------------------
// exclusive scan of cnt[] -> rowptr[] (3-kernel hierarchical scan, 1024/block)
__global__ __launch_bounds__(256) void scan1_k(const int* __restrict__ cnt,
                                               int* __restrict__ stmp,
                                               int* __restrict__ bsum, int n) {
    __shared__ int lds[256];
    int t = threadIdx.x, b = blockIdx.x;
    int base = b * 1024 + t * 4;
    int v0 = (base + 0 < n) ? cnt[base + 0] : 0;
    int v1 = (base + 1 < n) ? cnt[base + 1] : 0;
    int v2 = (base + 2 < n) ? cnt[base + 2] : 0;
    int v3 = (base + 3 < n) ? cnt[base + 3] : 0;
    int p0 = v0, p1 = p0 + v1, p2 = p1 + v2, p3 = p2 + v3;
    lds[t] = p3;
    __syncthreads();
    int own = p3;
    for (int o = 1; o < 256; o <<= 1) {
        int x = (t >= o) ? lds[t - o] : 0;
        __syncthreads();
        lds[t] += x;
        __syncthreads();
    }
    int excl = lds[t] - own;                 // exclusive prefix of this thread
    if (base + 0 < n) stmp[base + 0] = excl + p0;   // block-inclusive
    if (base + 1 < n) stmp[base + 1] = excl + p1;
    if (base + 2 < n) stmp[base + 2] = excl + p2;
    if (base + 3 < n) stmp[base + 3] = excl + p3;
    if (t == 255) bsum[b] = lds[255];
}

__global__ void scan2_k(int* __restrict__ bsum, int nb) {
    __shared__ int lds[128];
    int t = threadIdx.x;
    int v = (t < nb) ? bsum[t] : 0;
    lds[t] = v;
    __syncthreads();
    for (int o = 1; o < 128; o <<= 1) {
        int x = (t >= o) ? lds[t - o] : 0;
        __syncthreads();
        lds[t] += x;
        __syncthreads();
    }
    if (t < nb) bsum[t] = lds[t] - v;        // exclusive
}

// rowptr from scan pieces; also dinv = rsqrt(deg) with deg = cnt+1 (self loop)
__global__ void scan3_k(const int* __restrict__ cnt, const int* __restrict__ stmp,
                        const int* __restrict__ bsum, int* __restrict__ rowptr,
                        float* __restrict__ dinv, int n, int E) {
    int i = blockIdx.x * 256 + threadIdx.x;
    if (i < n) {
        rowptr[i] = stmp[i] - cnt[i] + bsum[i >> 10];
        dinv[i] = rsqrtf((float)(cnt[i] + 1));
    }
    if (i == 0) rowptr[n] = E;
}

// atomic-free fill: slot = rowptr[dst] + ord; packed {src, norm} per edge.
__global__ void fill_k(const int* __restrict__ src32, const int* __restrict__ dst32,
                       const int* __restrict__ ord, const int* __restrict__ rowptr,
                       const float* __restrict__ dinv,
                       int2* __restrict__ csre, int E) {
    int e = blockIdx.x * 256 + threadIdx.x;
    if (e >= E) return;
    int s = src32[e], d = dst32[e];
    int slot = rowptr[d] + ord[e];
    float w = dinv[s] * dinv[d];
    csre[slot] = make_int2(s, __float_as_int(w));
}

// ---------------------------------------------------------------------------
__device__ inline unsigned pack_bf16(float a, float b) {
    unsigned ua = __float_as_uint(a);
    unsigned ub = __float_as_uint(b);
    ua += 0x7FFFu + ((ua >> 16) & 1u);       // RNE
    ub += 0x7FFFu + ((ub >> 16) & 1u);
    return (ua >> 16) | (ub & 0xFFFF0000u);
}

__device__ inline void unp_bf16(unsigned u, float& a, float& b) {
    a = __uint_as_float(u << 16);
    b = __uint_as_float(u & 0xFFFF0000u);
}

// ---------------------------------------------------------------------------
// GEMM: Y[nrows x NCOL] = f(X)[nrows x 128] @ W[128 x NCOL]  (fp32, vector ALU)
// 64-row tile, X-tile transposed in LDS (padded), W K-tiled 32 rows at a time.
// OUT_BF16: thread owns adjacent column pairs {2tx,2tx+1}+32*c2 and emits one
// packed u32 per pair -> u32 index j of a row holds cols (2j, 2j+1). LDS B
// reads: 16 distinct banks x 4-lane same-address broadcast -> conflict-free.
// FUSE_BN applies relu(bn(.)) during X staging: x*sc + sh, sh = be - m*sc;
// each thread's staged feature columns (t&31)*4+j are loop-invariant.
template <int NCOL, bool FUSE_BN, bool OUT_BF16>
__global__ __launch_bounds__(256) void gemm_k(const float* __restrict__ X,
                                              const float* __restrict__ W,
                                              void* __restrict__ Yv, int nrows,
                                              const float* __restrict__ stats,
                                              const float* __restrict__ gam,
                                              const float* __restrict__ bet) {
    constexpr int KDIM = 128;
    constexpr int TM = 64;
    constexpr int KT = 32;
    constexpr int CPT = NCOL / 16;           // cols per thread: 8 or 2
    __shared__ float xt[KDIM][TM + 4];       // transposed X tile, padded
    __shared__ float wt[KT][NCOL];

    const int t = threadIdx.x;
    const int ty = t >> 4, tx = t & 15;
    const int row0 = blockIdx.x * TM;

    float sc[4], sh[4];
    if (FUSE_BN) {
        float invn = 1.0f / (float)nrows;
        int k4c = (t & 31) * 4;
#pragma unroll
        for (int j = 0; j < 4; ++j) {
            int c = k4c + j;
            float m = stats[c] * invn;
            float var = stats[128 + c] * invn - m * m;
            float s = rsqrtf(var + BN_EPS) * gam[c];
            sc[j] = s;
            sh[j] = bet[c] - m * s;
        }
    }

    const float4* X4 = (const float4*)X;
#pragma unroll
    for (int i = 0; i < 8; ++i) {
        int idx = i * 256 + t;               // 0..2047, coalesced
        int r = idx >> 5;                    // 32 float4 per row
        int k4 = idx & 31;                   // == t & 31 (invariant)
        int gr = row0 + r;
        if (gr > nrows - 1) gr = nrows - 1;
        float4 v = X4[(size_t)gr * 32 + k4];
        if (FUSE_BN) {
            v.x = fmaxf(fmaf(v.x, sc[0], sh[0]), 0.0f);
            v.y = fmaxf(fmaf(v.y, sc[1], sh[1]), 0.0f);
            v.z = fmaxf(fmaf(v.z, sc[2], sh[2]), 0.0f);
            v.w = fmaxf(fmaf(v.w, sc[3], sh[3]), 0.0f);
        }
        xt[k4 * 4 + 0][r] = v.x;
        xt[k4 * 4 + 1][r] = v.y;
        xt[k4 * 4 + 2][r] = v.z;
        xt[k4 * 4 + 3][r] = v.w;
    }

    int colIdx[CPT];
#pragma unroll
    for (int c = 0; c < CPT; ++c)
        colIdx[c] = OUT_BF16 ? (2 * tx + (c & 1) + 32 * (c >> 1)) : (tx + 16 * c);

    float acc[4][CPT];
#pragma unroll
    for (int r = 0; r < 4; ++r)
#pragma unroll
        for (int c = 0; c < CPT; ++c) acc[r][c] = 0.0f;

    const float4* W4 = (const float4*)W;
    for (int kt = 0; kt < KDIM / KT; ++kt) {
        __syncthreads();                     // xt ready / wt no longer in use
        constexpr int F4 = KT * NCOL / 4;
#pragma unroll
        for (int i = 0; i < F4 / 256; ++i) {
            int idx = i * 256 + t;
            int r = idx / (NCOL / 4);
            int c4 = idx % (NCOL / 4);
            float4 v = W4[(size_t)(kt * KT + r) * (NCOL / 4) + c4];
            *(float4*)&wt[r][c4 * 4] = v;
        }
        __syncthreads();
#pragma unroll
        for (int k = 0; k < KT; ++k) {
            float4 a = *(const float4*)&xt[kt * KT + k][ty * 4];
            float av[4] = {a.x, a.y, a.z, a.w};
            float bv[CPT];
#pragma unroll
            for (int c = 0; c < CPT; ++c) bv[c] = wt[k][colIdx[c]];
#pragma unroll
            for (int r = 0; r < 4; ++r)
#pragma unroll
                for (int c = 0; c < CPT; ++c)
                    acc[r][c] = fmaf(av[r], bv[c], acc[r][c]);
        }
    }

#pragma unroll
    for (int r = 0; r < 4; ++r) {
        int gr = row0 + ty * 4 + r;
        if (gr < nrows) {
            if (OUT_BF16) {
                unsigned* Y16 = (unsigned*)Yv;
#pragma unroll
                for (int c2 = 0; c2 < CPT / 2; ++c2)
                    Y16[(size_t)gr * (NCOL / 2) + tx + 16 * c2] =
                        pack_bf16(acc[r][2 * c2], acc[r][2 * c2 + 1]);
            } else {
                float* Y = (float*)Yv;
#pragma unroll
                for (int c = 0; c < CPT; ++c)
                    Y[(size_t)gr * NCOL + tx + 16 * c] = acc[r][c];
            }
        }
    }
}

// ---------------------------------------------------------------------------
// CSR aggregation over bf16 feature rows (D=128, 256B/row):
// out[i] = dinv[i]^2*H[i] + sum_e norm_e*H[src_e] + bias, fp32 accumulate.
// 16 lanes per node, each lane owns 8 consecutive cols (one uint4 = 8 bf16).
__global__ __launch_bounds__(256) void agg16_k(const unsigned* __restrict__ H16,
                                               const float* __restrict__ dinv,
                                               const int* __restrict__ rowptr,
                                               const int2* __restrict__ csre,
                                               const float* __restrict__ bias,
                                               float* __restrict__ out, int n) {
    int g = threadIdx.x >> 4;
    int lane = threadIdx.x & 15;
    int node = blockIdx.x * 16 + g;
    if (node >= n) return;

    const uint4* H4 = (const uint4*)H16;     // 16 uint4 per row
    float di = dinv[node];
    float w0 = di * di;
    float acc[8];
    {
        uint4 sv = H4[(size_t)node * 16 + lane];
        float a, b;
        unp_bf16(sv.x, a, b); acc[0] = w0 * a; acc[1] = w0 * b;
        unp_bf16(sv.y, a, b); acc[2] = w0 * a; acc[3] = w0 * b;
        unp_bf16(sv.z, a, b); acc[4] = w0 * a; acc[5] = w0 * b;
        unp_bf16(sv.w, a, b); acc[6] = w0 * a; acc[7] = w0 * b;
    }

    int s = rowptr[node], e = rowptr[node + 1];
    for (; s + 1 < e; s += 2) {
        int2 ev0 = csre[s];
        int2 ev1 = csre[s + 1];
        uint4 h0 = H4[(size_t)ev0.x * 16 + lane];
        uint4 h1 = H4[(size_t)ev1.x * 16 + lane];
        float wa = __int_as_float(ev0.y);
        float wb = __int_as_float(ev1.y);
        float a, b;
        unp_bf16(h0.x, a, b); acc[0] = fmaf(wa, a, acc[0]); acc[1] = fmaf(wa, b, acc[1]);
        unp_bf16(h0.y, a, b); acc[2] = fmaf(wa, a, acc[2]); acc[3] = fmaf(wa, b, acc[3]);
        unp_bf16(h0.z, a, b); acc[4] = fmaf(wa, a, acc[4]); acc[5] = fmaf(wa, b, acc[5]);
        unp_bf16(h0.w, a, b); acc[6] = fmaf(wa, a, acc[6]); acc[7] = fmaf(wa, b, acc[7]);
        unp_bf16(h1.x, a, b); acc[0] = fmaf(wb, a, acc[0]); acc[1] = fmaf(wb, b, acc[1]);
        unp_bf16(h1.y, a, b); acc[2] = fmaf(wb, a, acc[2]); acc[3] = fmaf(wb, b, acc[3]);
        unp_bf16(h1.z, a, b); acc[4] = fmaf(wb, a, acc[4]); acc[5] = fmaf(wb, b, acc[5]);
        unp_bf16(h1.w, a, b); acc[6] = fmaf(wb, a, acc[6]); acc[7] = fmaf(wb, b, acc[7]);
    }
    if (s < e) {
        int2 ev = csre[s];
        uint4 hv = H4[(size_t)ev.x * 16 + lane];
        float w = __int_as_float(ev.y);
        float a, b;
        unp_bf16(hv.x, a, b); acc[0] = fmaf(w, a, acc[0]); acc[1] = fmaf(w, b, acc[1]);
        unp_bf16(hv.y, a, b); acc[2] = fmaf(w, a, acc[2]); acc[3] = fmaf(w, b, acc[3]);
        unp_bf16(hv.z, a, b); acc[4] = fmaf(w, a, acc[4]); acc[5] = fmaf(w, b, acc[5]);
        unp_bf16(hv.w, a, b); acc[6] = fmaf(w, a, acc[6]); acc[7] = fmaf(w, b, acc[7]);
    }

    const float4* B4 = (const float4*)bias;
    float4 b0 = B4[2 * lane], b1 = B4[2 * lane + 1];
    float4* O4 = (float4*)out;
    O4[(size_t)node * 32 + 2 * lane] =
        make_float4(acc[0] + b0.x, acc[1] + b0.y, acc[2] + b0.z, acc[3] + b0.w);
    O4[(size_t)node * 32 + 2 * lane + 1] =
        make_float4(acc[4] + b1.x, acc[5] + b1.y, acc[6] + b1.z, acc[7] + b1.w);
}

// ---------------------------------------------------------------------------
// CSR aggregation fp32 (layer 2, D=32): unchanged from round 8/9.
template <int F4>
__global__ __launch_bounds__(256) void agg_k(const float* __restrict__ H,
                                             const float* __restrict__ dinv,
                                             const int* __restrict__ rowptr,
                                             const int2* __restrict__ csre,
                                             const float* __restrict__ bias,
                                             float* __restrict__ out, int n) {
    constexpr int GP = 256 / F4;
    int g = threadIdx.x / F4;
    int lane = threadIdx.x % F4;
    int node = blockIdx.x * GP + g;
    if (node >= n) return;

    const float4* H4 = (const float4*)H;
    float di = dinv[node];
    float w0 = di * di;
    float4 v = H4[(size_t)node * F4 + lane];
    float ax = v.x * w0, ay = v.y * w0, az = v.z * w0, aw = v.w * w0;

    int s = rowptr[node], e = rowptr[node + 1];
    for (; s + 3 < e; s += 4) {
        int2 ev0 = csre[s];
        int2 ev1 = csre[s + 1];
        int2 ev2 = csre[s + 2];
        int2 ev3 = csre[s + 3];
        float4 h0 = H4[(size_t)ev0.x * F4 + lane];
        float4 h1 = H4[(size_t)ev1.x * F4 + lane];
        float4 h2 = H4[(size_t)ev2.x * F4 + lane];
        float4 h3 = H4[(size_t)ev3.x * F4 + lane];
        float wa = __int_as_float(ev0.y);
        float wb = __int_as_float(ev1.y);
        float wc = __int_as_float(ev2.y);
        float wd = __int_as_float(ev3.y);
        ax = fmaf(wa, h0.x, ax); ay = fmaf(wa, h0.y, ay);
        az = fmaf(wa, h0.z, az); aw = fmaf(wa, h0.w, aw);
        ax = fmaf(wb, h1.x, ax); ay = fmaf(wb, h1.y, ay);
        az = fmaf(wb, h1.z, az); aw = fmaf(wb, h1.w, aw);
        ax = fmaf(wc, h2.x, ax); ay = fmaf(wc, h2.y, ay);
        az = fmaf(wc, h2.z, az); aw = fmaf(wc, h2.w, aw);
        ax = fmaf(wd, h3.x, ax); ay = fmaf(wd, h3.y, ay);
        az = fmaf(wd, h3.z, az); aw = fmaf(wd, h3.w, aw);
    }
    for (; s < e; ++s) {
        int2 ev = csre[s];
        float w = __int_as_float(ev.y);
        float4 hv = H4[(size_t)ev.x * F4 + lane];
        ax = fmaf(w, hv.x, ax);
        ay = fmaf(w, hv.y, ay);
        az = fmaf(w, hv.z, az);
        aw = fmaf(w, hv.w, aw);
    }
    float4 b4 = ((const float4*)bias)[lane];
    float4 o = make_float4(ax + b4.x, ay + b4.y, az + b4.z, aw + b4.w);
    ((float4*)out)[(size_t)node * F4 + lane] = o;
}

// ---------------------------------------------------------------------------
// BatchNorm stats over node axis (sum, sumsq per column) -> stats[256]
__global__ __launch_bounds__(256) void bnstats_k(const float* __restrict__ X,
                                                 float* __restrict__ stats, int n) {
    __shared__ float ls[256], ls2[256];
    int t = threadIdx.x;
    int col = t & 127;
    int half = t >> 7;
    float s = 0.0f, s2 = 0.0f;
    for (int r = blockIdx.x * 2 + half; r < n; r += gridDim.x * 2) {
        float v = X[(size_t)r * 128 + col];
        s += v;
        s2 = fmaf(v, v, s2);
    }
    ls[t] = s; ls2[t] = s2;
    __syncthreads();
    if (t < 128) {
        s = ls[t] + ls[t + 128];
        s2 = ls2[t] + ls2[t + 128];
        atomicAdd(&stats[col], s);
        atomicAdd(&stats[128 + col], s2);
    }
}

// ---------------------------------------------------------------------------
// log_softmax over rows of 32 (one 32-lane group per row)
__global__ __launch_bounds__(256) void lsm_k(const float* __restrict__ X,
                                             float* __restrict__ out, int n) {
    int t = threadIdx.x;
    int g = t >> 5;
    int lane = t & 31;
    int row = blockIdx.x * 8 + g;
    if (row >= n) return;
    float v = X[(size_t)row * 32 + lane];
    float m = v;
    for (int o = 16; o; o >>= 1) m = fmaxf(m, __shfl_xor(m, o, 32));
    float ex = __expf(v - m);
    float s = ex;
    for (int o = 16; o; o >>= 1) s += __shfl_xor(s, o, 32);
    out[(size_t)row * 32 + lane] = v - m - logf(s);
}

// ---------------------------------------------------------------------------
extern "C" void kernel_launch(void* const* d_in, const int* in_sizes, int n_in,
                              void* d_out, int out_size, void* d_ws, size_t ws_size,
                              hipStream_t stream) {
    const int N = in_sizes[0] / 128;
    const int E = in_sizes[1] / 2;

    const float* x   = (const float*)d_in[0];
    const void*  edg = d_in[1];
    const float* W0  = (const float*)d_in[2];
    const float* b0  = (const float*)d_in[3];
    const float* g0  = (const float*)d_in[4];
    const float* be0 = (const float*)d_in[5];
    const float* W1  = (const float*)d_in[6];
    const float* b1  = (const float*)d_in[7];
    const float* g1  = (const float*)d_in[8];
    const float* be1 = (const float*)d_in[9];
    const float* W2  = (const float*)d_in[10];
    const float* b2  = (const float*)d_in[11];
    float* out = (float*)d_out;

    char* ws = (char*)d_ws;
    size_t off = 0;
    auto alloc = [&](size_t bytes) {
        char* p = ws + off;
        off = (off + bytes + 255) & ~(size_t)255;
        return p;
    };
    int*   flag   = (int*)  alloc(16);
    float* dinv   = (float*)alloc((size_t)N * 4);
    int*   cnt    = (int*)  alloc((size_t)N * 4);
    int*   src32  = (int*)  alloc((size_t)E * 4);
    int*   dst32  = (int*)  alloc((size_t)E * 4);
    int*   ord    = (int*)  alloc((size_t)E * 4);
    int*   rowptr = (int*)  alloc((size_t)(N + 1) * 4);
    int*   stmp   = (int*)  alloc((size_t)N * 4);
    int*   bsum   = (int*)  alloc(512);
    int2*  csre   = (int2*) alloc((size_t)E * 8);
    float* h      = (float*)alloc((size_t)N * 128 * 4);  // bf16 h16 (layers 0/1) / fp32 h (layer 2)
    float* agg    = (float*)alloc((size_t)N * 128 * 4);
    float* stats  = (float*)alloc(1024 * 4);   // [sum0|sq0|sum1|sq1] x 128
    float* stats0 = stats;
    float* stats1 = stats + 256;
    unsigned* h16 = (unsigned*)h;
    (void)ws_size; (void)n_in; (void)out_size;

    dim3 B(256);
    int gN   = (N + 255) / 256;
    int gE   = (E + 255) / 256;
    int nb   = (N + 1023) / 1024;
    int gGm  = (N + 63) / 64;
    int gA16 = (N + 15) / 16;
    int gA8  = (N + 31) / 32;
    int gLSM = (N + 7) / 8;

    // graph construction (shared across the 3 conv layers)
    detect_k<<<dim3(1), dim3(64), 0, stream>>>((const int*)edg, flag);
    init_k<<<gN, B, 0, stream>>>(cnt, stats, N);
    convert_count_k<<<gE, B, 0, stream>>>(edg, E, flag, src32, dst32, ord, cnt);
    scan1_k<<<nb, B, 0, stream>>>(cnt, stmp, bsum, N);
    scan2_k<<<dim3(1), dim3(128), 0, stream>>>(bsum, nb);
    scan3_k<<<gN, B, 0, stream>>>(cnt, stmp, bsum, rowptr, dinv, N, E);
    fill_k<<<gE, B, 0, stream>>>(src32, dst32, ord, rowptr, dinv, csre, E);

    // layer 0: h16 = bf16(x@W0); agg0 = A_hat h + b0 (fp32); stats0 over agg0
    gemm_k<128, false, true><<<gGm, B, 0, stream>>>(x, W0, h16, N, nullptr, nullptr, nullptr);
    agg16_k<<<gA16, B, 0, stream>>>(h16, dinv, rowptr, csre, b0, agg, N);
    bnstats_k<<<dim3(512), B, 0, stream>>>(agg, stats0, N);

    // layer 1: h16 = bf16(relu(bn0(agg0))@W1); agg1; stats1
    gemm_k<128, true, true><<<gGm, B, 0, stream>>>(agg, W1, h16, N, stats0, g0, be0);
    agg16_k<<<gA16, B, 0, stream>>>(h16, dinv, rowptr, csre, b1, agg, N);
    bnstats_k<<<dim3(512), B, 0, stream>>>(agg, stats1, N);

    // layer 2 (fp32 throughout): h = relu(bn1(agg1))@W2; agg2 (N,32); lsm
    gemm_k<32, true, false><<<gGm, B, 0, stream>>>(agg, W2, h, N, stats1, g1, be1);
    agg_k<8><<<gA8, B, 0, stream>>>(h, dinv, rowptr, csre, b2, agg, N);
    lsm_k<<<gLSM, B, 0, stream>>>(agg, out, N);
}

// Round 15
// 550.548 us; speedup vs baseline: 1.6257x; 1.1325x over previous
//
#include <hip/hip_runtime.h>
#include <hip/hip_bf16.h>
#include <cstdint>
#include <cstddef>

#define BN_EPS 1e-5f
#define CNTS 32   // cnt stride (ints): one counter per 128B line

typedef __attribute__((ext_vector_type(8))) short bf16x8;
typedef __attribute__((ext_vector_type(4))) float f32x4;

// ---------------------------------------------------------------------------
__global__ void detect_k(const int* __restrict__ edges, int* __restrict__ flag) {
    int t = threadIdx.x;            // 64 threads
    int v = edges[2 * t + 1];
    unsigned long long b = __ballot(v == 0);
    if (t == 0) flag[0] = (b == ~0ULL) ? 1 : 0;
}

// zero strided histogram (n32 = N*CNTS ints) + BN stats buffers
__global__ void init_k(int* __restrict__ cnt, float* __restrict__ stats, int n32) {
    int i = blockIdx.x * 256 + threadIdx.x;
    if (i < n32) cnt[i] = 0;
    if (i < 1024) stats[i] = 0.0f;
}

// One atomic per edge; return value doubles as the within-dst ordinal.
// cnt is padded CNTS ints apart so each counter owns a cache line ->
// same-line RMW serialization at the L3 slice drops ~16x.
__global__ void convert_count_k(const void* __restrict__ edges, int E, const int* __restrict__ flag,
                                int* __restrict__ src32, int* __restrict__ dst32,
                                int* __restrict__ ord, int* __restrict__ cnt) {
    int e = blockIdx.x * 256 + threadIdx.x;
    if (e >= E) return;
    int s, d;
    if (flag[0]) {
        const long long* p = (const long long*)edges;
        s = (int)p[e]; d = (int)p[(size_t)E + e];
    } else {
        const int* p = (const int*)edges;
        s = p[e]; d = p[(size_t)E + e];
    }
    src32[e] = s; dst32[e] = d;
    ord[e] = atomicAdd(&cnt[d * CNTS], 1);
}

// ---------------------------------------------------------------------------
// exclusive scan of strided cnt[] -> rowptr[]
__global__ __launch_bounds__(256) void scan1_k(const int* __restrict__ cnt,
                                               int* __restrict__ stmp,
                                               int* __restrict__ bsum, int n) {
    __shared__ int lds[256];
    int t = threadIdx.x, b = blockIdx.x;
    int base = b * 1024 + t * 4;
    int v0 = (base + 0 < n) ? cnt[(base + 0) * CNTS] : 0;
    int v1 = (base + 1 < n) ? cnt[(base + 1) * CNTS] : 0;
    int v2 = (base + 2 < n) ? cnt[(base + 2) * CNTS] : 0;
    int v3 = (base + 3 < n) ? cnt[(base + 3) * CNTS] : 0;
    int p0 = v0, p1 = p0 + v1, p2 = p1 + v2, p3 = p2 + v3;
    lds[t] = p3;
    __syncthreads();
    int own = p3;
    for (int o = 1; o < 256; o <<= 1) {
        int x = (t >= o) ? lds[t - o] : 0;
        __syncthreads();
        lds[t] += x;
        __syncthreads();
    }
    int excl = lds[t] - own;
    if (base + 0 < n) stmp[base + 0] = excl + p0;
    if (base + 1 < n) stmp[base + 1] = excl + p1;
    if (base + 2 < n) stmp[base + 2] = excl + p2;
    if (base + 3 < n) stmp[base + 3] = excl + p3;
    if (t == 255) bsum[b] = lds[255];
}

__global__ void scan2_k(int* __restrict__ bsum, int nb) {
    __shared__ int lds[128];
    int t = threadIdx.x;
    int v = (t < nb) ? bsum[t] : 0;
    lds[t] = v;
    __syncthreads();
    for (int o = 1; o < 128; o <<= 1) {
        int x = (t >= o) ? lds[t - o] : 0;
        __syncthreads();
        lds[t] += x;
        __syncthreads();
    }
    if (t < nb) bsum[t] = lds[t] - v;        // exclusive
}

__global__ void scan3_k(const int* __restrict__ cnt, const int* __restrict__ stmp,
                        const int* __restrict__ bsum, int* __restrict__ rowptr,
                        float* __restrict__ dinv, int n, int E) {
    int i = blockIdx.x * 256 + threadIdx.x;
    if (i < n) {
        int c = cnt[i * CNTS];
        rowptr[i] = stmp[i] - c + bsum[i >> 10];
        dinv[i] = rsqrtf((float)(c + 1));
    }
    if (i == 0) rowptr[n] = E;
}

// atomic-free fill: slot = rowptr[dst] + ord; packed {src, norm} per edge.
__global__ void fill_k(const int* __restrict__ src32, const int* __restrict__ dst32,
                       const int* __restrict__ ord, const int* __restrict__ rowptr,
                       const float* __restrict__ dinv,
                       int2* __restrict__ csre, int E) {
    int e = blockIdx.x * 256 + threadIdx.x;
    if (e >= E) return;
    int s = src32[e], d = dst32[e];
    int slot = rowptr[d] + ord[e];
    float w = dinv[s] * dinv[d];
    csre[slot] = make_int2(s, __float_as_int(w));
}

// ---------------------------------------------------------------------------
__device__ inline unsigned pack_bf16(float a, float b) {
    unsigned ua = __float_as_uint(a);
    unsigned ub = __float_as_uint(b);
    ua += 0x7FFFu + ((ua >> 16) & 1u);       // RNE
    ub += 0x7FFFu + ((ub >> 16) & 1u);
    return (ua >> 16) | (ub & 0xFFFF0000u);
}

__device__ inline void unp_bf16(unsigned u, float& a, float& b) {
    a = __uint_as_float(u << 16);
    b = __uint_as_float(u & 0xFFFF0000u);
}

// ---------------------------------------------------------------------------
// W[128][128] fp32 -> Wt16[col][64] u32 (bf16 pair (k=2j, 2j+1)); 32 blocks.
__global__ void wprep_k(const float* __restrict__ W, unsigned* __restrict__ Wt16) {
    int idx = blockIdx.x * 256 + threadIdx.x;   // 0..8191
    int j = idx >> 7;          // k-pair 0..63
    int c = idx & 127;         // col
    float a = W[(size_t)(2 * j) * 128 + c];
    float b = W[(size_t)(2 * j + 1) * 128 + c];
    Wt16[(size_t)c * 64 + j] = pack_bf16(a, b);
}

// ---------------------------------------------------------------------------
// MFMA GEMM (layers 0/1): Y16 = bf16( f(X)[nrows x 128] @ W[128 x 128] )
// 64-row tile, 4 waves (16 rows each), whole K=128 staged in LDS as bf16.
// LDS layout: row-major 256B rows, XOR-swizzled: byte ^= (row&7)<<4 ->
// ds_read_b128 of a column-slice is 2-way conflict (free, m136).
// mfma_f32_16x16x32_bf16 layouts: A/B: lane holds (m|n)=lane&15,
// k=(lane>>4)*8+j contiguous; C/D: col=lane&15, row=(lane>>4)*4+reg.
// FUSE_BN: relu(bn(x)) = max(x*sc+sh,0) applied during staging; this
// thread's staged k-columns (t&15)*8+j are loop-invariant.
template <bool FUSE_BN>
__global__ __launch_bounds__(256) void gemm_mfma_k(const float* __restrict__ X,
                                                   const unsigned* __restrict__ Wt16,
                                                   unsigned* __restrict__ Y16, int nrows,
                                                   const float* __restrict__ stats,
                                                   const float* __restrict__ gam,
                                                   const float* __restrict__ bet) {
    __shared__ __align__(16) char lds[(64 + 128) * 256];   // A 16KB + B 32KB
    char* Alds = lds;
    char* Blds = lds + 64 * 256;

    const int t = threadIdx.x;
    const int lane = t & 63;
    const int wid = t >> 6;
    const int row0 = blockIdx.x * 64;

    float sc[8], sh[8];
    if (FUSE_BN) {
        float invn = 1.0f / (float)nrows;
        int c0 = (t & 15) * 8;
#pragma unroll
        for (int j = 0; j < 8; ++j) {
            int c = c0 + j;
            float m = stats[c] * invn;
            float var = stats[128 + c] * invn - m * m;
            float s = rsqrtf(var + BN_EPS) * gam[c];
            sc[j] = s;
            sh[j] = bet[c] - m * s;
        }
    }

    // stage A: 1024 x 16B; idx = r*16+kg, kg = t&15 fixed per thread
    const float4* X4 = (const float4*)X;
    const int kg = t & 15;
#pragma unroll
    for (int i = 0; i < 4; ++i) {
        int r = i * 16 + (t >> 4);
        int gr = row0 + r;
        if (gr > nrows - 1) gr = nrows - 1;
        float4 v0 = X4[(size_t)gr * 32 + kg * 2];
        float4 v1 = X4[(size_t)gr * 32 + kg * 2 + 1];
        float f[8] = {v0.x, v0.y, v0.z, v0.w, v1.x, v1.y, v1.z, v1.w};
        if (FUSE_BN) {
#pragma unroll
            for (int j = 0; j < 8; ++j) f[j] = fmaxf(fmaf(f[j], sc[j], sh[j]), 0.0f);
        }
        uint4 p = make_uint4(pack_bf16(f[0], f[1]), pack_bf16(f[2], f[3]),
                             pack_bf16(f[4], f[5]), pack_bf16(f[6], f[7]));
        int byte = (r * 256 + kg * 16) ^ ((r & 7) << 4);
        *(uint4*)(Alds + byte) = p;
    }
    // stage B: 2048 x 16B, Wt16 read linearly coalesced
    const uint4* Wg4 = (const uint4*)Wt16;
#pragma unroll
    for (int i = 0; i < 8; ++i) {
        int idx = i * 256 + t;
        int wr = idx >> 4;
        uint4 v = Wg4[idx];
        int byte = (wr * 256 + (idx & 15) * 16) ^ ((wr & 7) << 4);
        *(uint4*)(Blds + byte) = v;
    }
    __syncthreads();

    f32x4 acc[8];
#pragma unroll
    for (int ct = 0; ct < 8; ++ct) acc[ct] = (f32x4){0.f, 0.f, 0.f, 0.f};

    const int rA = wid * 16 + (lane & 15);
    const int g = lane >> 4;
#pragma unroll
    for (int kt = 0; kt < 4; ++kt) {
        int abyte = (rA * 256 + kt * 64 + g * 16) ^ ((rA & 7) << 4);
        bf16x8 a = *(const bf16x8*)(Alds + abyte);
#pragma unroll
        for (int ct = 0; ct < 8; ++ct) {
            int brow = ct * 16 + (lane & 15);
            int bbyte = (brow * 256 + kt * 64 + g * 16) ^ ((brow & 7) << 4);
            bf16x8 b = *(const bf16x8*)(Blds + bbyte);
            acc[ct] = __builtin_amdgcn_mfma_f32_16x16x32_bf16(a, b, acc[ct], 0, 0, 0);
        }
    }

    // epilogue: pair adjacent cols via shfl_xor(1), write packed bf16 u32
    const int c = lane & 15;
#pragma unroll
    for (int ct = 0; ct < 8; ++ct) {
#pragma unroll
        for (int r = 0; r < 4; ++r) {
            float own = acc[ct][r];
            float oth = __shfl_xor(own, 1);
            int gr = row0 + wid * 16 + (lane >> 4) * 4 + r;
            if (!(c & 1) && gr < nrows)
                Y16[(size_t)gr * 64 + (ct * 16 + c) / 2] = pack_bf16(own, oth);
        }
    }
}

// ---------------------------------------------------------------------------
// VALU GEMM, layer 2 only: Y[nrows x 32] = relu(bn(X))[nrows x 128] @ W[128 x 32]
template <int NCOL, bool FUSE_BN>
__global__ __launch_bounds__(256) void gemm_k(const float* __restrict__ X,
                                              const float* __restrict__ W,
                                              float* __restrict__ Y, int nrows,
                                              const float* __restrict__ stats,
                                              const float* __restrict__ gam,
                                              const float* __restrict__ bet) {
    constexpr int KDIM = 128;
    constexpr int TM = 64;
    constexpr int KT = 32;
    constexpr int CPT = NCOL / 16;
    __shared__ float xt[KDIM][TM + 4];
    __shared__ float wt[KT][NCOL];

    const int t = threadIdx.x;
    const int ty = t >> 4, tx = t & 15;
    const int row0 = blockIdx.x * TM;

    float sc[4], sh[4];
    if (FUSE_BN) {
        float invn = 1.0f / (float)nrows;
        int k4c = (t & 31) * 4;
#pragma unroll
        for (int j = 0; j < 4; ++j) {
            int c = k4c + j;
            float m = stats[c] * invn;
            float var = stats[128 + c] * invn - m * m;
            float s = rsqrtf(var + BN_EPS) * gam[c];
            sc[j] = s;
            sh[j] = bet[c] - m * s;
        }
    }

    const float4* X4 = (const float4*)X;
#pragma unroll
    for (int i = 0; i < 8; ++i) {
        int idx = i * 256 + t;
        int r = idx >> 5;
        int k4 = idx & 31;
        int gr = row0 + r;
        if (gr > nrows - 1) gr = nrows - 1;
        float4 v = X4[(size_t)gr * 32 + k4];
        if (FUSE_BN) {
            v.x = fmaxf(fmaf(v.x, sc[0], sh[0]), 0.0f);
            v.y = fmaxf(fmaf(v.y, sc[1], sh[1]), 0.0f);
            v.z = fmaxf(fmaf(v.z, sc[2], sh[2]), 0.0f);
            v.w = fmaxf(fmaf(v.w, sc[3], sh[3]), 0.0f);
        }
        xt[k4 * 4 + 0][r] = v.x;
        xt[k4 * 4 + 1][r] = v.y;
        xt[k4 * 4 + 2][r] = v.z;
        xt[k4 * 4 + 3][r] = v.w;
    }

    float acc[4][CPT];
#pragma unroll
    for (int r = 0; r < 4; ++r)
#pragma unroll
        for (int c = 0; c < CPT; ++c) acc[r][c] = 0.0f;

    const float4* W4 = (const float4*)W;
    for (int kt = 0; kt < KDIM / KT; ++kt) {
        __syncthreads();
        constexpr int F4 = KT * NCOL / 4;
#pragma unroll
        for (int i = 0; i < F4 / 256; ++i) {
            int idx = i * 256 + t;
            int r = idx / (NCOL / 4);
            int c4 = idx % (NCOL / 4);
            float4 v = W4[(size_t)(kt * KT + r) * (NCOL / 4) + c4];
            *(float4*)&wt[r][c4 * 4] = v;
        }
        __syncthreads();
#pragma unroll
        for (int k = 0; k < KT; ++k) {
            float4 a = *(const float4*)&xt[kt * KT + k][ty * 4];
            float av[4] = {a.x, a.y, a.z, a.w};
            float bv[CPT];
#pragma unroll
            for (int c = 0; c < CPT; ++c) bv[c] = wt[k][tx + 16 * c];
#pragma unroll
            for (int r = 0; r < 4; ++r)
#pragma unroll
                for (int c = 0; c < CPT; ++c)
                    acc[r][c] = fmaf(av[r], bv[c], acc[r][c]);
        }
    }

#pragma unroll
    for (int r = 0; r < 4; ++r) {
        int gr = row0 + ty * 4 + r;
        if (gr < nrows) {
#pragma unroll
            for (int c = 0; c < CPT; ++c)
                Y[(size_t)gr * NCOL + tx + 16 * c] = acc[r][c];
        }
    }
}

// ---------------------------------------------------------------------------
// CSR aggregation over bf16 feature rows (D=128, 256B/row), fp32 accumulate.
__global__ __launch_bounds__(256) void agg16_k(const unsigned* __restrict__ H16,
                                               const float* __restrict__ dinv,
                                               const int* __restrict__ rowptr,
                                               const int2* __restrict__ csre,
                                               const float* __restrict__ bias,
                                               float* __restrict__ out, int n) {
    int g = threadIdx.x >> 4;
    int lane = threadIdx.x & 15;
    int node = blockIdx.x * 16 + g;
    if (node >= n) return;

    const uint4* H4 = (const uint4*)H16;
    float di = dinv[node];
    float w0 = di * di;
    float acc[8];
    {
        uint4 sv = H4[(size_t)node * 16 + lane];
        float a, b;
        unp_bf16(sv.x, a, b); acc[0] = w0 * a; acc[1] = w0 * b;
        unp_bf16(sv.y, a, b); acc[2] = w0 * a; acc[3] = w0 * b;
        unp_bf16(sv.z, a, b); acc[4] = w0 * a; acc[5] = w0 * b;
        unp_bf16(sv.w, a, b); acc[6] = w0 * a; acc[7] = w0 * b;
    }

    int s = rowptr[node], e = rowptr[node + 1];
    for (; s + 1 < e; s += 2) {
        int2 ev0 = csre[s];
        int2 ev1 = csre[s + 1];
        uint4 h0 = H4[(size_t)ev0.x * 16 + lane];
        uint4 h1 = H4[(size_t)ev1.x * 16 + lane];
        float wa = __int_as_float(ev0.y);
        float wb = __int_as_float(ev1.y);
        float a, b;
        unp_bf16(h0.x, a, b); acc[0] = fmaf(wa, a, acc[0]); acc[1] = fmaf(wa, b, acc[1]);
        unp_bf16(h0.y, a, b); acc[2] = fmaf(wa, a, acc[2]); acc[3] = fmaf(wa, b, acc[3]);
        unp_bf16(h0.z, a, b); acc[4] = fmaf(wa, a, acc[4]); acc[5] = fmaf(wa, b, acc[5]);
        unp_bf16(h0.w, a, b); acc[6] = fmaf(wa, a, acc[6]); acc[7] = fmaf(wa, b, acc[7]);
        unp_bf16(h1.x, a, b); acc[0] = fmaf(wb, a, acc[0]); acc[1] = fmaf(wb, b, acc[1]);
        unp_bf16(h1.y, a, b); acc[2] = fmaf(wb, a, acc[2]); acc[3] = fmaf(wb, b, acc[3]);
        unp_bf16(h1.z, a, b); acc[4] = fmaf(wb, a, acc[4]); acc[5] = fmaf(wb, b, acc[5]);
        unp_bf16(h1.w, a, b); acc[6] = fmaf(wb, a, acc[6]); acc[7] = fmaf(wb, b, acc[7]);
    }
    if (s < e) {
        int2 ev = csre[s];
        uint4 hv = H4[(size_t)ev.x * 16 + lane];
        float w = __int_as_float(ev.y);
        float a, b;
        unp_bf16(hv.x, a, b); acc[0] = fmaf(w, a, acc[0]); acc[1] = fmaf(w, b, acc[1]);
        unp_bf16(hv.y, a, b); acc[2] = fmaf(w, a, acc[2]); acc[3] = fmaf(w, b, acc[3]);
        unp_bf16(hv.z, a, b); acc[4] = fmaf(w, a, acc[4]); acc[5] = fmaf(w, b, acc[5]);
        unp_bf16(hv.w, a, b); acc[6] = fmaf(w, a, acc[6]); acc[7] = fmaf(w, b, acc[7]);
    }

    const float4* B4 = (const float4*)bias;
    float4 b0 = B4[2 * lane], b1 = B4[2 * lane + 1];
    float4* O4 = (float4*)out;
    O4[(size_t)node * 32 + 2 * lane] =
        make_float4(acc[0] + b0.x, acc[1] + b0.y, acc[2] + b0.z, acc[3] + b0.w);
    O4[(size_t)node * 32 + 2 * lane + 1] =
        make_float4(acc[4] + b1.x, acc[5] + b1.y, acc[6] + b1.z, acc[7] + b1.w);
}

// ---------------------------------------------------------------------------
// CSR aggregation fp32 (layer 2, D=32)
template <int F4>
__global__ __launch_bounds__(256) void agg_k(const float* __restrict__ H,
                                             const float* __restrict__ dinv,
                                             const int* __restrict__ rowptr,
                                             const int2* __restrict__ csre,
                                             const float* __restrict__ bias,
                                             float* __restrict__ out, int n) {
    constexpr int GP = 256 / F4;
    int g = threadIdx.x / F4;
    int lane = threadIdx.x % F4;
    int node = blockIdx.x * GP + g;
    if (node >= n) return;

    const float4* H4 = (const float4*)H;
    float di = dinv[node];
    float w0 = di * di;
    float4 v = H4[(size_t)node * F4 + lane];
    float ax = v.x * w0, ay = v.y * w0, az = v.z * w0, aw = v.w * w0;

    int s = rowptr[node], e = rowptr[node + 1];
    for (; s + 3 < e; s += 4) {
        int2 ev0 = csre[s];
        int2 ev1 = csre[s + 1];
        int2 ev2 = csre[s + 2];
        int2 ev3 = csre[s + 3];
        float4 h0 = H4[(size_t)ev0.x * F4 + lane];
        float4 h1 = H4[(size_t)ev1.x * F4 + lane];
        float4 h2 = H4[(size_t)ev2.x * F4 + lane];
        float4 h3 = H4[(size_t)ev3.x * F4 + lane];
        float wa = __int_as_float(ev0.y);
        float wb = __int_as_float(ev1.y);
        float wc = __int_as_float(ev2.y);
        float wd = __int_as_float(ev3.y);
        ax = fmaf(wa, h0.x, ax); ay = fmaf(wa, h0.y, ay);
        az = fmaf(wa, h0.z, az); aw = fmaf(wa, h0.w, aw);
        ax = fmaf(wb, h1.x, ax); ay = fmaf(wb, h1.y, ay);
        az = fmaf(wb, h1.z, az); aw = fmaf(wb, h1.w, aw);
        ax = fmaf(wc, h2.x, ax); ay = fmaf(wc, h2.y, ay);
        az = fmaf(wc, h2.z, az); aw = fmaf(wc, h2.w, aw);
        ax = fmaf(wd, h3.x, ax); ay = fmaf(wd, h3.y, ay);
        az = fmaf(wd, h3.z, az); aw = fmaf(wd, h3.w, aw);
    }
    for (; s < e; ++s) {
        int2 ev = csre[s];
        float w = __int_as_float(ev.y);
        float4 hv = H4[(size_t)ev.x * F4 + lane];
        ax = fmaf(w, hv.x, ax);
        ay = fmaf(w, hv.y, ay);
        az = fmaf(w, hv.z, az);
        aw = fmaf(w, hv.w, aw);
    }
    float4 b4 = ((const float4*)bias)[lane];
    float4 o = make_float4(ax + b4.x, ay + b4.y, az + b4.z, aw + b4.w);
    ((float4*)out)[(size_t)node * F4 + lane] = o;
}

// ---------------------------------------------------------------------------
__global__ __launch_bounds__(256) void bnstats_k(const float* __restrict__ X,
                                                 float* __restrict__ stats, int n) {
    __shared__ float ls[256], ls2[256];
    int t = threadIdx.x;
    int col = t & 127;
    int half = t >> 7;
    float s = 0.0f, s2 = 0.0f;
    for (int r = blockIdx.x * 2 + half; r < n; r += gridDim.x * 2) {
        float v = X[(size_t)r * 128 + col];
        s += v;
        s2 = fmaf(v, v, s2);
    }
    ls[t] = s; ls2[t] = s2;
    __syncthreads();
    if (t < 128) {
        s = ls[t] + ls[t + 128];
        s2 = ls2[t] + ls2[t + 128];
        atomicAdd(&stats[col], s);
        atomicAdd(&stats[128 + col], s2);
    }
}

// ---------------------------------------------------------------------------
__global__ __launch_bounds__(256) void lsm_k(const float* __restrict__ X,
                                             float* __restrict__ out, int n) {
    int t = threadIdx.x;
    int g = t >> 5;
    int lane = t & 31;
    int row = blockIdx.x * 8 + g;
    if (row >= n) return;
    float v = X[(size_t)row * 32 + lane];
    float m = v;
    for (int o = 16; o; o >>= 1) m = fmaxf(m, __shfl_xor(m, o, 32));
    float ex = __expf(v - m);
    float s = ex;
    for (int o = 16; o; o >>= 1) s += __shfl_xor(s, o, 32);
    out[(size_t)row * 32 + lane] = v - m - logf(s);
}

// ---------------------------------------------------------------------------
extern "C" void kernel_launch(void* const* d_in, const int* in_sizes, int n_in,
                              void* d_out, int out_size, void* d_ws, size_t ws_size,
                              hipStream_t stream) {
    const int N = in_sizes[0] / 128;
    const int E = in_sizes[1] / 2;

    const float* x   = (const float*)d_in[0];
    const void*  edg = d_in[1];
    const float* W0  = (const float*)d_in[2];
    const float* b0  = (const float*)d_in[3];
    const float* g0  = (const float*)d_in[4];
    const float* be0 = (const float*)d_in[5];
    const float* W1  = (const float*)d_in[6];
    const float* b1  = (const float*)d_in[7];
    const float* g1  = (const float*)d_in[8];
    const float* be1 = (const float*)d_in[9];
    const float* W2  = (const float*)d_in[10];
    const float* b2  = (const float*)d_in[11];
    float* out = (float*)d_out;

    char* ws = (char*)d_ws;
    size_t off = 0;
    auto alloc = [&](size_t bytes) {
        char* p = ws + off;
        off = (off + bytes + 255) & ~(size_t)255;
        return p;
    };
    int*      flag   = (int*)     alloc(16);
    float*    dinv   = (float*)   alloc((size_t)N * 4);
    int*      cnt    = (int*)     alloc((size_t)N * CNTS * 4);   // 128B/counter
    int*      src32  = (int*)     alloc((size_t)E * 4);
    int*      dst32  = (int*)     alloc((size_t)E * 4);
    int*      ord    = (int*)     alloc((size_t)E * 4);
    int*      rowptr = (int*)     alloc((size_t)(N + 1) * 4);
    int*      stmp   = (int*)     alloc((size_t)N * 4);
    int*      bsum   = (int*)     alloc(512);
    int2*     csre   = (int2*)    alloc((size_t)E * 8);
    float*    h      = (float*)   alloc((size_t)N * 128 * 4);  // bf16 h16 / fp32 h
    float*    agg    = (float*)   alloc((size_t)N * 128 * 4);
    float*    stats  = (float*)   alloc(1024 * 4);
    unsigned* wt16   = (unsigned*)alloc(128 * 64 * 4);         // W^T bf16, reused
    float*    stats0 = stats;
    float*    stats1 = stats + 256;
    unsigned* h16    = (unsigned*)h;
    (void)ws_size; (void)n_in; (void)out_size;

    dim3 B(256);
    int gE   = (E + 255) / 256;
    int gN   = (N + 255) / 256;
    int gNC  = (N * CNTS + 255) / 256;
    int nb   = (N + 1023) / 1024;
    int gGm  = (N + 63) / 64;
    int gA16 = (N + 15) / 16;
    int gA8  = (N + 31) / 32;
    int gLSM = (N + 7) / 8;

    // graph construction (shared across the 3 conv layers)
    detect_k<<<dim3(1), dim3(64), 0, stream>>>((const int*)edg, flag);
    init_k<<<gNC, B, 0, stream>>>(cnt, stats, N * CNTS);
    convert_count_k<<<gE, B, 0, stream>>>(edg, E, flag, src32, dst32, ord, cnt);
    scan1_k<<<nb, B, 0, stream>>>(cnt, stmp, bsum, N);
    scan2_k<<<dim3(1), dim3(128), 0, stream>>>(bsum, nb);
    scan3_k<<<gN, B, 0, stream>>>(cnt, stmp, bsum, rowptr, dinv, N, E);
    fill_k<<<gE, B, 0, stream>>>(src32, dst32, ord, rowptr, dinv, csre, E);

    // layer 0: h16 = bf16(x@W0) via MFMA; agg0; stats0
    wprep_k<<<dim3(32), B, 0, stream>>>(W0, wt16);
    gemm_mfma_k<false><<<gGm, B, 0, stream>>>(x, wt16, h16, N, nullptr, nullptr, nullptr);
    agg16_k<<<gA16, B, 0, stream>>>(h16, dinv, rowptr, csre, b0, agg, N);
    bnstats_k<<<dim3(512), B, 0, stream>>>(agg, stats0, N);

    // layer 1: h16 = bf16(relu(bn0(agg0))@W1) via MFMA; agg1; stats1
    wprep_k<<<dim3(32), B, 0, stream>>>(W1, wt16);
    gemm_mfma_k<true><<<gGm, B, 0, stream>>>(agg, wt16, h16, N, stats0, g0, be0);
    agg16_k<<<gA16, B, 0, stream>>>(h16, dinv, rowptr, csre, b1, agg, N);
    bnstats_k<<<dim3(512), B, 0, stream>>>(agg, stats1, N);

    // layer 2 (fp32 throughout): h = relu(bn1(agg1))@W2; agg2 (N,32); lsm
    gemm_k<32, true><<<gGm, B, 0, stream>>>(agg, W2, h, N, stats1, g1, be1);
    agg_k<8><<<gA8, B, 0, stream>>>(h, dinv, rowptr, csre, b2, agg, N);
    lsm_k<<<gLSM, B, 0, stream>>>(agg, out, N);
}